// Round 7
// baseline (2325.147 us; speedup 1.0000x reference)
//
#include <hip/hip_runtime.h>
#include <hip/hip_bf16.h>

// NBFNet Bellman-Ford pass, MI355X. N=20000, E=200000, B=4, K=32, D=32, R=36, L=4.
// x layout: [n][d][b] (b innermost) -> gather reads one dwordx4 per edge per lane.
#define N_NODES 20000
#define N_EDGES 200000
#define BB 4
#define KK 32
#define DD 32
#define RR 36
#define LL 4
#define NCHUNKS (N_NODES / 16)   // 1250 = 250 * 5
#define NBLK 79                  // ceil(20000/256)

// ---------------- ws layout (element offsets, 4B units) ----------------
constexpr size_t OFF_X0   = 0;                                        // float[N*D*B], x[(n*32+d)*4+b]
constexpr size_t OFF_X1   = OFF_X0 + (size_t)BB * N_NODES * DD;
constexpr size_t OFF_RP   = OFF_X1 + (size_t)BB * N_NODES * DD;       // int[N+1]
constexpr size_t OFF_CUR  = OFF_RP + 20032;                           // int[N]
constexpr size_t OFF_ES   = OFF_CUR + N_NODES;                        // int[E] src | type<<16
constexpr size_t OFF_DEG  = OFF_ES + N_EDGES;                         // float[N] 1/deg
constexpr size_t OFF_SC   = OFF_DEG + N_NODES;                        // float[N] scale
constexpr size_t OFF_INV  = OFF_SC + N_NODES;                         // float[N] 1/max(scale,.01)
constexpr size_t OFF_BS   = OFF_INV + N_NODES;                        // int[128] block sums
constexpr size_t OFF_BL   = OFF_BS + 128;                             // float[128] block log sums
constexpr size_t OFF_BO   = OFF_BL + 128;                             // int[128] block offsets
constexpr size_t OFF_MEAN = OFF_BO + 128;                             // float[16]
constexpr size_t OFF_REL  = OFF_MEAN + 16;                            // float[L*R*D*B] [l][ty][d][b]
constexpr size_t OFF_PW   = OFF_REL + (size_t)LL * RR * BB * DD;      // float[L*16*832]
constexpr size_t OFF_F    = OFF_PW + (size_t)LL * 16 * 832;           // float4[NCHUNKS*32*64] = 41 MB

// ---------------- prep kernels ----------------

__global__ void k_init(const int* __restrict__ h_index, const int* __restrict__ r_index,
                       const float* __restrict__ query_emb, float* __restrict__ x0,
                       int* __restrict__ cursor) {
    int i = blockIdx.x * blockDim.x + threadIdx.x;
    int stride = gridDim.x * blockDim.x;
    for (int t = i; t < N_NODES; t += stride) cursor[t] = 0;
    for (int t = i; t < BB * N_NODES * DD; t += stride) {
        int b = t & 3; int d = (t >> 2) & 31; int n = t >> 7;
        float v = 0.f;
        if (n == h_index[b]) v = query_emb[r_index[b] * DD + d];
        x0[t] = v;
    }
}

__global__ void k_hist(const int* __restrict__ ei, int* __restrict__ cursor) {
    int e = blockIdx.x * blockDim.x + threadIdx.x;
    if (e < N_EDGES) atomicAdd(&cursor[ei[N_EDGES + e]], 1);
}

// per-block partial sums of deg histogram + log(deg)
__global__ void k_part(const int* __restrict__ cursor, int* __restrict__ bsum,
                       float* __restrict__ blog) {
    __shared__ int si[256];
    __shared__ float sf2[256];
    int tid = threadIdx.x;
    int i = blockIdx.x * 256 + tid;
    int v = (i < N_NODES) ? cursor[i] : 0;
    float lg = (i < N_NODES) ? logf((float)(v + 1)) : 0.f;
    si[tid] = v; sf2[tid] = lg;
    __syncthreads();
    for (int off = 128; off > 0; off >>= 1) {
        if (tid < off) { si[tid] += si[tid + off]; sf2[tid] += sf2[tid + off]; }
        __syncthreads();
    }
    if (tid == 0) { bsum[blockIdx.x] = si[0]; blog[blockIdx.x] = sf2[0]; }
}

// single small block: scan the 79 block sums; total log -> mean
__global__ void k_scan2(const int* __restrict__ bsum, const float* __restrict__ blog,
                        int* __restrict__ boff, float* __restrict__ meanw) {
    __shared__ int si[128];
    __shared__ float sf2[128];
    int t = threadIdx.x;
    int v = (t < NBLK) ? bsum[t] : 0;
    float lg = (t < NBLK) ? blog[t] : 0.f;
    si[t] = v; sf2[t] = lg;
    __syncthreads();
    for (int off = 1; off < 128; off <<= 1) {
        int tv = (t >= off) ? si[t - off] : 0;
        float tf = (t >= off) ? sf2[t - off] : 0.f;
        __syncthreads();
        si[t] += tv; sf2[t] += tf;
        __syncthreads();
    }
    if (t < NBLK) boff[t] = si[t] - v;                      // exclusive
    if (t == 127) meanw[0] = sf2[127] / (float)N_NODES;     // mean(log deg)
}

// per-block scan + global offset -> row_ptr/cursor; rdeg/scale/inv
__global__ void k_final(int* __restrict__ cursor, int* __restrict__ row_ptr,
                        const int* __restrict__ boff, const float* __restrict__ meanw,
                        float* __restrict__ rdeg, float* __restrict__ scale,
                        float* __restrict__ invs) {
    __shared__ int si[256];
    int tid = threadIdx.x;
    int i = blockIdx.x * 256 + tid;
    int v = (i < N_NODES) ? cursor[i] : 0;
    si[tid] = v;
    __syncthreads();
    for (int off = 1; off < 256; off <<= 1) {
        int tv = (tid >= off) ? si[tid - off] : 0;
        __syncthreads();
        si[tid] += tv;
        __syncthreads();
    }
    int rp = boff[blockIdx.x] + si[tid] - v;   // exclusive prefix
    if (i < N_NODES) {
        row_ptr[i] = rp;
        cursor[i] = rp;
        float dg = (float)(v + 1);
        float sc = logf(dg) / meanw[0];
        rdeg[i] = 1.f / dg;
        scale[i] = sc;
        invs[i] = 1.f / fmaxf(sc, 0.01f);
    }
    if (i == 0) row_ptr[N_NODES] = N_EDGES;
}

__global__ void k_scatter(const int* __restrict__ ei, const int* __restrict__ et,
                          int* __restrict__ cursor, int* __restrict__ es) {
    int e = blockIdx.x * blockDim.x + threadIdx.x;
    if (e < N_EDGES) {
        int dnode = ei[N_EDGES + e];
        int p = atomicAdd(&cursor[dnode], 1);
        es[p] = ei[e] | (et[e] << 16);
    }
}

// rel tables [l][ty][d][b] + prepped conv weights.
// pw layout per (l, w), w in [0,16) covering outputs o = {w*2, w*2+1}:
//   r in [0,64):  x-part.  j = r>>1, o = w*2 + (r&1), col = j
//   r in [64,832): feats.  r2=r-64; jj=r2/24; rem=r2%24; p=rem>>1 (=f*3+k);
//                  o = w*2 + (rem&1); col = 32 + (jj*4 + p/3)*3 + p%3
__global__ void k_prep_w(const float* __restrict__ query_emb, const int* __restrict__ r_index,
                         const float* __restrict__ rel_W, const float* __restrict__ rel_b,
                         const float* __restrict__ conv_W,
                         float* __restrict__ rel_all, float* __restrict__ pw) {
    int i = blockIdx.x * blockDim.x + threadIdx.x;
    const int NREL = LL * BB * RR * DD;
    if (i < NREL) {
        int d = i & 31;
        int ty = (i >> 5) % RR;
        int b = (i / (32 * RR)) & 3;
        int l = i / (32 * RR * BB);
        const float* q = query_emb + r_index[b] * DD;
        const float* w = rel_W + ((size_t)l * RR * DD + ty * DD + d) * DD;
        float acc = rel_b[l * RR * DD + ty * DD + d];
        #pragma unroll
        for (int k2 = 0; k2 < DD; ++k2) acc = fmaf(q[k2], w[k2], acc);
        rel_all[(((size_t)l * RR + ty) * DD + d) * BB + b] = acc;
    } else {
        int i2 = i - NREL;
        if (i2 >= LL * 16 * 832) return;
        int r = i2 % 832; int lw = i2 / 832;
        int w = lw & 15, l = lw >> 4;
        int o, col;
        if (r < 64) { col = r >> 1; o = w * 2 + (r & 1); }
        else {
            int r2 = r - 64;
            int jj = r2 / 24, rem = r2 % 24;
            int p = rem >> 1;
            o = w * 2 + (rem & 1);
            col = DD + (jj * 4 + p / 3) * 3 + (p % 3);
        }
        pw[i2] = conv_W[(size_t)(l * DD + o) * (13 * DD) + col];
    }
}

// ---------------- gather + PNA kernel ----------------
// Wave per node (grid-stride). lane = d + 32*par; parity halves process alternate
// edges (4-deep unroll = 8 x-row dwordx4 loads in flight per wave); shfl_xor(32) combine.
// Writes F transposed: Fq[(chunk*32 + d)*64 + task] = {mean,max,min,std}.
__launch_bounds__(256, 6)
__global__ void k_gather(const float* __restrict__ xin, float4* __restrict__ Fq,
                         const int* __restrict__ row_ptr, const int* __restrict__ es,
                         const float* __restrict__ rel_l, const float* __restrict__ rdeg,
                         const int* __restrict__ h_index, const int* __restrict__ r_index,
                         const float* __restrict__ query_emb) {
    __shared__ __align__(16) float s_rel[RR * BB * DD];   // 18432 B, [ty][d][b]
    const int tid = threadIdx.x;
    {   // stage rel table once per block
        const float4* p4 = (const float4*)rel_l;
        float4* s4 = (float4*)s_rel;
        for (int i = tid; i < RR * BB * DD / 4; i += 256) s4[i] = p4[i];
    }
    const int lane = tid & 63;
    const int d = lane & 31;
    const int par = lane >> 5;
    int hb[4]; float qv[4];
    #pragma unroll
    for (int b = 0; b < 4; ++b) {
        hb[b] = h_index[b];
        qv[b] = query_emb[r_index[b] * DD + d];
    }
    __syncthreads();

    const int nwaves = gridDim.x * 4;
    for (int n = blockIdx.x * 4 + (tid >> 6); n < N_NODES; n += nwaves) {
        float sa[4], sq[4], mx[4], mn[4];
        #pragma unroll
        for (int b = 0; b < 4; ++b) {
            float bv = (n == hb[b]) ? qv[b] : 0.f;
            float bs = par ? 0.f : bv;        // count boundary message once in sum/sq
            sa[b] = bs; sq[b] = bs * bv; mx[b] = bv; mn[b] = bv;
        }
        auto proc = [&](int ee) {
            int pk = es[ee];
            float4 xv = *(const float4*)(xin + ((size_t)(pk & 0xFFFF) * DD + d) * 4);
            float4 rv = *(const float4*)(s_rel + (((pk >> 16) * DD) + d) * 4);
            #pragma unroll
            for (int b = 0; b < 4; ++b) {
                float m = (&xv.x)[b] * (&rv.x)[b];
                sa[b] += m; sq[b] = fmaf(m, m, sq[b]);
                mx[b] = fmaxf(mx[b], m); mn[b] = fminf(mn[b], m);
            }
        };
        int e0 = row_ptr[n], e1 = row_ptr[n + 1];
        int e = e0 + par;                        // parity-strided: 2 edges per step
        for (; e + 6 < e1; e += 8) { proc(e); proc(e + 2); proc(e + 4); proc(e + 6); }
        for (; e < e1; e += 2) proc(e);
        #pragma unroll
        for (int b = 0; b < 4; ++b) {
            sa[b] += __shfl_xor(sa[b], 32);
            sq[b] += __shfl_xor(sq[b], 32);
            mx[b] = fmaxf(mx[b], __shfl_xor(mx[b], 32));
            mn[b] = fminf(mn[b], __shfl_xor(mn[b], 32));
        }
        float rd_ = rdeg[n];
        float mean[4], sd[4];
        #pragma unroll
        for (int b = 0; b < 4; ++b) {
            mean[b] = sa[b] * rd_;
            float sm = sq[b] * rd_;
            sd[b] = sqrtf(fmaxf(sm - mean[b] * mean[b], 1e-6f));
        }
        const int chunk = n >> 4, nl = n & 15;
        int tA = nl * 4 + par * 2;               // each half writes 2 tasks
        float4 fA, fB;
        fA.x = par ? mean[2] : mean[0]; fA.y = par ? mx[2] : mx[0];
        fA.z = par ? mn[2] : mn[0];     fA.w = par ? sd[2] : sd[0];
        fB.x = par ? mean[3] : mean[1]; fB.y = par ? mx[3] : mx[1];
        fB.z = par ? mn[3] : mn[1];     fB.w = par ? sd[3] : sd[1];
        Fq[(size_t)(chunk * 32 + d) * 64 + tA] = fA;
        Fq[(size_t)(chunk * 32 + d) * 64 + tA + 1] = fB;
    }
}

// ---------------- conv kernel ----------------
// Grid 250 x 1024 (16 waves = 4 waves/SIMD at 1 block/CU — the r6 fix: grid 250
// can never exceed 1 block/CU, so put all 16 waves in the block).
// Block owns 5 chunks (T=5). Wave w computes outputs {w*2, w*2+1}; lane = task.
// Per-CU LDS weight traffic unchanged vs r6 (16 waves x 208 quads = 3328 b128),
// FMA/SIMD unchanged (4 waves x 4160), but 4-way latency interleave + explicit
// ping-pong prefetch of Fq (cfA/cfB) hides the per-jj load latency.
__launch_bounds__(1024, 4)
__global__ void k_conv(const float* __restrict__ xin, float* __restrict__ xout,
                       const float4* __restrict__ Fq, const float* __restrict__ pw_l,
                       const float* __restrict__ scale, const float* __restrict__ invs,
                       const float* __restrict__ conv_b_l) {
    __shared__ __align__(16) float4 s_pw[16 * 208];   // 53248 B
    const int tid = threadIdx.x;
    {
        const float4* p4 = (const float4*)pw_l;
        for (int i = tid; i < 16 * 208; i += 1024) s_pw[i] = p4[i];
    }
    const int wq = __builtin_amdgcn_readfirstlane(tid >> 6);   // 0..15
    const int lane = tid & 63;
    const float4* wx = s_pw + wq * 208;       // x-part: 16 quads (quad j2: j=2*j2,2*j2+1 x 2 outs)
    const float4* wf = wx + 16;               // feats: 6 quads per jj (pair p = f*3+k)
    float bx = conv_b_l[wq * 2], by = conv_b_l[wq * 2 + 1];
    __syncthreads();

    const int set = blockIdx.x;               // chunks set*5 .. set*5+4
    const int nl2 = lane >> 2, b2 = lane & 3;

    float y[5][3][2];
    #pragma unroll
    for (int cc = 0; cc < 5; ++cc) {
        y[cc][0][0] = bx; y[cc][0][1] = by;
        y[cc][1][0] = 0.f; y[cc][1][1] = 0.f;
        y[cc][2][0] = 0.f; y[cc][2][1] = 0.f;
    }

    // ---- x part: K rows 0..31 ([n][d][b] layout -> strided dword loads, L1/L2-hot) ----
    #pragma unroll 2
    for (int jg = 0; jg < 8; ++jg) {
        float cxv[5][4];
        #pragma unroll
        for (int cc = 0; cc < 5; ++cc) {
            int n = (set * 5 + cc) * 16 + nl2;
            const float* xb = xin + (size_t)n * 128 + b2;
            #pragma unroll
            for (int dj = 0; dj < 4; ++dj)
                cxv[cc][dj] = xb[(jg * 4 + dj) * 4];
        }
        #pragma unroll
        for (int dj = 0; dj < 4; ++dj) {
            int j = jg * 4 + dj;
            float4 q = wx[j >> 1];
            float wlo = (j & 1) ? q.z : q.x;
            float whi = (j & 1) ? q.w : q.y;
            #pragma unroll
            for (int cc = 0; cc < 5; ++cc) {
                float cv = cxv[cc][dj];
                y[cc][0][0] = fmaf(cv, wlo, y[cc][0][0]);
                y[cc][0][1] = fmaf(cv, whi, y[cc][0][1]);
            }
        }
    }

    // ---- feats: 32 d-blocks (f = mean/max/min/std, k = 1/scale/inv sets) ----
    auto fmab = [&](const float4* cf, int jj) {
        const float4* wp = wf + jj * 6;
        #pragma unroll
        for (int f = 0; f < 4; ++f) {
            #pragma unroll
            for (int k = 0; k < 3; ++k) {
                int p = f * 3 + k;
                float4 q = wp[p >> 1];
                float wlo = (p & 1) ? q.z : q.x;
                float whi = (p & 1) ? q.w : q.y;
                #pragma unroll
                for (int cc = 0; cc < 5; ++cc) {
                    float cv = (&cf[cc].x)[f];
                    y[cc][k][0] = fmaf(cv, wlo, y[cc][k][0]);
                    y[cc][k][1] = fmaf(cv, whi, y[cc][k][1]);
                }
            }
        }
    };
    float4 cfA[5], cfB[5];
    #pragma unroll
    for (int cc = 0; cc < 5; ++cc)
        cfA[cc] = Fq[(size_t)((set * 5 + cc) * 32 + 0) * 64 + lane];
    #pragma unroll 4
    for (int jj = 0; jj < 32; jj += 2) {
        #pragma unroll
        for (int cc = 0; cc < 5; ++cc)
            cfB[cc] = Fq[(size_t)((set * 5 + cc) * 32 + jj + 1) * 64 + lane];
        fmab(cfA, jj);
        if (jj + 2 < 32) {
            #pragma unroll
            for (int cc = 0; cc < 5; ++cc)
                cfA[cc] = Fq[(size_t)((set * 5 + cc) * 32 + jj + 2) * 64 + lane];
        }
        fmab(cfB, jj + 1);
    }

    // ---- epilogue: out[n][o][b] scalar stores ----
    #pragma unroll
    for (int cc = 0; cc < 5; ++cc) {
        int n = (set * 5 + cc) * 16 + nl2;
        float scn = scale[n], ivn = invs[n];
        float* xo = xout + (size_t)n * 128 + b2;
        float v0 = fmaxf(0.f, y[cc][0][0] + scn * y[cc][1][0] + ivn * y[cc][2][0]);
        float v1 = fmaxf(0.f, y[cc][0][1] + scn * y[cc][1][1] + ivn * y[cc][2][1]);
        xo[(wq * 2) * 4] = v0;
        xo[(wq * 2 + 1) * 4] = v1;
    }
}

// ---------------- final scoring ----------------
__global__ void k_score(const float* __restrict__ xL, const float* __restrict__ query_emb,
                        const int* __restrict__ r_index, const int* __restrict__ t_index,
                        const float* __restrict__ W1, const float* __restrict__ b1,
                        const float* __restrict__ W2, const float* __restrict__ b2,
                        float* __restrict__ out) {
    int bi = blockIdx.x;            // 0..127
    int b = bi >> 5, kk = bi & 31;
    int j = threadIdx.x;            // 0..63
    __shared__ float sf[64];
    int t = t_index[b * KK + kk];
    float f = (j < DD) ? xL[(size_t)t * 128 + j * 4 + b]
                       : query_emb[r_index[b] * DD + (j - DD)];
    sf[j] = f;
    __syncthreads();
    float acc = b1[j];
    #pragma unroll 8
    for (int i2 = 0; i2 < 64; ++i2) acc = fmaf(sf[i2], W1[j * 64 + i2], acc);
    float h = fmaxf(acc, 0.f);
    float prod = h * W2[j];
    #pragma unroll
    for (int off = 32; off > 0; off >>= 1) prod += __shfl_down(prod, off);
    if (j == 0) out[b * KK + kk] = prod + b2[0];
}

extern "C" void kernel_launch(void* const* d_in, const int* in_sizes, int n_in,
                              void* d_out, int out_size, void* d_ws, size_t ws_size,
                              hipStream_t stream) {
    const int* ei        = (const int*)d_in[0];
    const int* et        = (const int*)d_in[1];
    const int* h_index   = (const int*)d_in[2];
    const int* t_index   = (const int*)d_in[3];
    const int* r_index   = (const int*)d_in[4];
    const float* query_emb = (const float*)d_in[6];
    const float* rel_W   = (const float*)d_in[7];
    const float* rel_b   = (const float*)d_in[8];
    const float* conv_W  = (const float*)d_in[9];
    const float* conv_b  = (const float*)d_in[10];
    const float* W1      = (const float*)d_in[11];
    const float* b1      = (const float*)d_in[12];
    const float* W2      = (const float*)d_in[13];
    const float* b2      = (const float*)d_in[14];

    float* ws = (float*)d_ws;
    float* x0      = ws + OFF_X0;
    float* x1      = ws + OFF_X1;
    int*   row_ptr = (int*)(ws + OFF_RP);
    int*   cursor  = (int*)(ws + OFF_CUR);
    int*   es      = (int*)(ws + OFF_ES);
    float* rdeg    = ws + OFF_DEG;
    float* sc      = ws + OFF_SC;
    float* invs    = ws + OFF_INV;
    int*   bsum    = (int*)(ws + OFF_BS);
    float* blog    = ws + OFF_BL;
    int*   boff    = (int*)(ws + OFF_BO);
    float* meanw   = ws + OFF_MEAN;
    float* rel_all = ws + OFF_REL;
    float* pw      = ws + OFF_PW;
    float4* Fq     = (float4*)(ws + OFF_F);
    float* out     = (float*)d_out;

    // prep
    k_init<<<1024, 256, 0, stream>>>(h_index, r_index, query_emb, x0, cursor);
    k_hist<<<(N_EDGES + 255) / 256, 256, 0, stream>>>(ei, cursor);
    k_part<<<NBLK, 256, 0, stream>>>(cursor, bsum, blog);
    k_scan2<<<1, 128, 0, stream>>>(bsum, blog, boff, meanw);
    k_final<<<NBLK, 256, 0, stream>>>(cursor, row_ptr, boff, meanw, rdeg, sc, invs);
    k_scatter<<<(N_EDGES + 255) / 256, 256, 0, stream>>>(ei, et, cursor, es);
    const int NPREP = LL * BB * RR * DD + LL * 16 * 832;
    k_prep_w<<<(NPREP + 255) / 256, 256, 0, stream>>>(query_emb, r_index, rel_W, rel_b,
                                                      conv_W, rel_all, pw);

    // 4 BF layers, ping-pong x0/x1
    for (int l = 0; l < LL; ++l) {
        const float* xi = (l & 1) ? x1 : x0;
        float* xo = (l & 1) ? x0 : x1;
        k_gather<<<1536, 256, 0, stream>>>(xi, Fq, row_ptr, es,
                                           rel_all + (size_t)l * RR * BB * DD,
                                           rdeg, h_index, r_index, query_emb);
        k_conv<<<250, 1024, 0, stream>>>(xi, xo, Fq, pw + (size_t)l * 16 * 832,
                                         sc, invs, conv_b + l * DD);
    }

    k_score<<<BB * KK, 64, 0, stream>>>(x0, query_emb, r_index, t_index, W1, b1, W2, b2, out);
}

// Round 8
// 340.833 us; speedup vs baseline: 6.8220x; 6.8220x over previous
//
#include <hip/hip_runtime.h>
#include <hip/hip_bf16.h>

// NBFNet Bellman-Ford pass, MI355X. N=20000, E=200000, B=4, K=32, D=32, R=36, L=4.
// x layout: [n][d][b] (b innermost) -> gather reads one dwordx4 per edge per lane.
#define N_NODES 20000
#define N_EDGES 200000
#define BB 4
#define KK 32
#define DD 32
#define RR 36
#define LL 4
#define NCHUNKS (N_NODES / 16)   // 1250 = 250 * 5
#define NBLK 79                  // ceil(20000/256)

// ---------------- ws layout (element offsets, 4B units) ----------------
constexpr size_t OFF_X0   = 0;                                        // float[N*D*B], x[(n*32+d)*4+b]
constexpr size_t OFF_X1   = OFF_X0 + (size_t)BB * N_NODES * DD;
constexpr size_t OFF_RP   = OFF_X1 + (size_t)BB * N_NODES * DD;       // int[N+1]
constexpr size_t OFF_CUR  = OFF_RP + 20032;                           // int[N]
constexpr size_t OFF_ES   = OFF_CUR + N_NODES;                        // int[E] src | type<<16
constexpr size_t OFF_DEG  = OFF_ES + N_EDGES;                         // float[N] 1/deg
constexpr size_t OFF_SC   = OFF_DEG + N_NODES;                        // float[N] scale
constexpr size_t OFF_INV  = OFF_SC + N_NODES;                         // float[N] 1/max(scale,.01)
constexpr size_t OFF_BS   = OFF_INV + N_NODES;                        // int[128] block sums
constexpr size_t OFF_BL   = OFF_BS + 128;                             // float[128] block log sums
constexpr size_t OFF_BO   = OFF_BL + 128;                             // int[128] block offsets
constexpr size_t OFF_MEAN = OFF_BO + 128;                             // float[16]
constexpr size_t OFF_REL  = OFF_MEAN + 16;                            // float[L*R*D*B] [l][ty][d][b]
constexpr size_t OFF_PW   = OFF_REL + (size_t)LL * RR * BB * DD;      // float[L*16*832]
constexpr size_t OFF_F    = OFF_PW + (size_t)LL * 16 * 832;           // float4[NCHUNKS*32*64] = 41 MB

// ---------------- prep kernels ----------------

__global__ void k_init(const int* __restrict__ h_index, const int* __restrict__ r_index,
                       const float* __restrict__ query_emb, float* __restrict__ x0,
                       int* __restrict__ cursor) {
    int i = blockIdx.x * blockDim.x + threadIdx.x;
    int stride = gridDim.x * blockDim.x;
    for (int t = i; t < N_NODES; t += stride) cursor[t] = 0;
    for (int t = i; t < BB * N_NODES * DD; t += stride) {
        int b = t & 3; int d = (t >> 2) & 31; int n = t >> 7;
        float v = 0.f;
        if (n == h_index[b]) v = query_emb[r_index[b] * DD + d];
        x0[t] = v;
    }
}

__global__ void k_hist(const int* __restrict__ ei, int* __restrict__ cursor) {
    int e = blockIdx.x * blockDim.x + threadIdx.x;
    if (e < N_EDGES) atomicAdd(&cursor[ei[N_EDGES + e]], 1);
}

// per-block partial sums of deg histogram + log(deg)
__global__ void k_part(const int* __restrict__ cursor, int* __restrict__ bsum,
                       float* __restrict__ blog) {
    __shared__ int si[256];
    __shared__ float sf2[256];
    int tid = threadIdx.x;
    int i = blockIdx.x * 256 + tid;
    int v = (i < N_NODES) ? cursor[i] : 0;
    float lg = (i < N_NODES) ? logf((float)(v + 1)) : 0.f;
    si[tid] = v; sf2[tid] = lg;
    __syncthreads();
    for (int off = 128; off > 0; off >>= 1) {
        if (tid < off) { si[tid] += si[tid + off]; sf2[tid] += sf2[tid + off]; }
        __syncthreads();
    }
    if (tid == 0) { bsum[blockIdx.x] = si[0]; blog[blockIdx.x] = sf2[0]; }
}

// single small block: scan the 79 block sums; total log -> mean
__global__ void k_scan2(const int* __restrict__ bsum, const float* __restrict__ blog,
                        int* __restrict__ boff, float* __restrict__ meanw) {
    __shared__ int si[128];
    __shared__ float sf2[128];
    int t = threadIdx.x;
    int v = (t < NBLK) ? bsum[t] : 0;
    float lg = (t < NBLK) ? blog[t] : 0.f;
    si[t] = v; sf2[t] = lg;
    __syncthreads();
    for (int off = 1; off < 128; off <<= 1) {
        int tv = (t >= off) ? si[t - off] : 0;
        float tf = (t >= off) ? sf2[t - off] : 0.f;
        __syncthreads();
        si[t] += tv; sf2[t] += tf;
        __syncthreads();
    }
    if (t < NBLK) boff[t] = si[t] - v;                      // exclusive
    if (t == 127) meanw[0] = sf2[127] / (float)N_NODES;     // mean(log deg)
}

// per-block scan + global offset -> row_ptr/cursor; rdeg/scale/inv
__global__ void k_final(int* __restrict__ cursor, int* __restrict__ row_ptr,
                        const int* __restrict__ boff, const float* __restrict__ meanw,
                        float* __restrict__ rdeg, float* __restrict__ scale,
                        float* __restrict__ invs) {
    __shared__ int si[256];
    int tid = threadIdx.x;
    int i = blockIdx.x * 256 + tid;
    int v = (i < N_NODES) ? cursor[i] : 0;
    si[tid] = v;
    __syncthreads();
    for (int off = 1; off < 256; off <<= 1) {
        int tv = (tid >= off) ? si[tid - off] : 0;
        __syncthreads();
        si[tid] += tv;
        __syncthreads();
    }
    int rp = boff[blockIdx.x] + si[tid] - v;   // exclusive prefix
    if (i < N_NODES) {
        row_ptr[i] = rp;
        cursor[i] = rp;
        float dg = (float)(v + 1);
        float sc = logf(dg) / meanw[0];
        rdeg[i] = 1.f / dg;
        scale[i] = sc;
        invs[i] = 1.f / fmaxf(sc, 0.01f);
    }
    if (i == 0) row_ptr[N_NODES] = N_EDGES;
}

__global__ void k_scatter(const int* __restrict__ ei, const int* __restrict__ et,
                          int* __restrict__ cursor, int* __restrict__ es) {
    int e = blockIdx.x * blockDim.x + threadIdx.x;
    if (e < N_EDGES) {
        int dnode = ei[N_EDGES + e];
        int p = atomicAdd(&cursor[dnode], 1);
        es[p] = ei[e] | (et[e] << 16);
    }
}

// rel tables [l][ty][d][b] + prepped conv weights.
// pw layout per (l, w), w in [0,16) covering outputs o = {w*2, w*2+1}:
//   r in [0,64):  x-part.  j = r>>1, o = w*2 + (r&1), col = j
//   r in [64,832): feats.  r2=r-64; jj=r2/24; rem=r2%24; p=rem>>1 (=f*3+k);
//                  o = w*2 + (rem&1); col = 32 + (jj*4 + p/3)*3 + p%3
__global__ void k_prep_w(const float* __restrict__ query_emb, const int* __restrict__ r_index,
                         const float* __restrict__ rel_W, const float* __restrict__ rel_b,
                         const float* __restrict__ conv_W,
                         float* __restrict__ rel_all, float* __restrict__ pw) {
    int i = blockIdx.x * blockDim.x + threadIdx.x;
    const int NREL = LL * BB * RR * DD;
    if (i < NREL) {
        int d = i & 31;
        int ty = (i >> 5) % RR;
        int b = (i / (32 * RR)) & 3;
        int l = i / (32 * RR * BB);
        const float* q = query_emb + r_index[b] * DD;
        const float* w = rel_W + ((size_t)l * RR * DD + ty * DD + d) * DD;
        float acc = rel_b[l * RR * DD + ty * DD + d];
        #pragma unroll
        for (int k2 = 0; k2 < DD; ++k2) acc = fmaf(q[k2], w[k2], acc);
        rel_all[(((size_t)l * RR + ty) * DD + d) * BB + b] = acc;
    } else {
        int i2 = i - NREL;
        if (i2 >= LL * 16 * 832) return;
        int r = i2 % 832; int lw = i2 / 832;
        int w = lw & 15, l = lw >> 4;
        int o, col;
        if (r < 64) { col = r >> 1; o = w * 2 + (r & 1); }
        else {
            int r2 = r - 64;
            int jj = r2 / 24, rem = r2 % 24;
            int p = rem >> 1;
            o = w * 2 + (rem & 1);
            col = DD + (jj * 4 + p / 3) * 3 + (p % 3);
        }
        pw[i2] = conv_W[(size_t)(l * DD + o) * (13 * DD) + col];
    }
}

// ---------------- gather + PNA kernel ----------------
// Wave per node (grid-stride). lane = d + 32*par; parity halves process alternate
// edges (4-deep unroll = 8 x-row dwordx4 loads in flight per wave); shfl_xor(32) combine.
// Writes F transposed: Fq[(chunk*32 + d)*64 + task] = {mean,max,min,std}.
__launch_bounds__(256, 6)
__global__ void k_gather(const float* __restrict__ xin, float4* __restrict__ Fq,
                         const int* __restrict__ row_ptr, const int* __restrict__ es,
                         const float* __restrict__ rel_l, const float* __restrict__ rdeg,
                         const int* __restrict__ h_index, const int* __restrict__ r_index,
                         const float* __restrict__ query_emb) {
    __shared__ __align__(16) float s_rel[RR * BB * DD];   // 18432 B, [ty][d][b]
    const int tid = threadIdx.x;
    {   // stage rel table once per block
        const float4* p4 = (const float4*)rel_l;
        float4* s4 = (float4*)s_rel;
        for (int i = tid; i < RR * BB * DD / 4; i += 256) s4[i] = p4[i];
    }
    const int lane = tid & 63;
    const int d = lane & 31;
    const int par = lane >> 5;
    int hb[4]; float qv[4];
    #pragma unroll
    for (int b = 0; b < 4; ++b) {
        hb[b] = h_index[b];
        qv[b] = query_emb[r_index[b] * DD + d];
    }
    __syncthreads();

    const int nwaves = gridDim.x * 4;
    for (int n = blockIdx.x * 4 + (tid >> 6); n < N_NODES; n += nwaves) {
        float sa[4], sq[4], mx[4], mn[4];
        #pragma unroll
        for (int b = 0; b < 4; ++b) {
            float bv = (n == hb[b]) ? qv[b] : 0.f;
            float bs = par ? 0.f : bv;        // count boundary message once in sum/sq
            sa[b] = bs; sq[b] = bs * bv; mx[b] = bv; mn[b] = bv;
        }
        auto proc = [&](int ee) {
            int pk = es[ee];
            float4 xv = *(const float4*)(xin + ((size_t)(pk & 0xFFFF) * DD + d) * 4);
            float4 rv = *(const float4*)(s_rel + (((pk >> 16) * DD) + d) * 4);
            #pragma unroll
            for (int b = 0; b < 4; ++b) {
                float m = (&xv.x)[b] * (&rv.x)[b];
                sa[b] += m; sq[b] = fmaf(m, m, sq[b]);
                mx[b] = fmaxf(mx[b], m); mn[b] = fminf(mn[b], m);
            }
        };
        int e0 = row_ptr[n], e1 = row_ptr[n + 1];
        int e = e0 + par;                        // parity-strided: 2 edges per step
        for (; e + 6 < e1; e += 8) { proc(e); proc(e + 2); proc(e + 4); proc(e + 6); }
        for (; e < e1; e += 2) proc(e);
        #pragma unroll
        for (int b = 0; b < 4; ++b) {
            sa[b] += __shfl_xor(sa[b], 32);
            sq[b] += __shfl_xor(sq[b], 32);
            mx[b] = fmaxf(mx[b], __shfl_xor(mx[b], 32));
            mn[b] = fminf(mn[b], __shfl_xor(mn[b], 32));
        }
        float rd_ = rdeg[n];
        float mean[4], sd[4];
        #pragma unroll
        for (int b = 0; b < 4; ++b) {
            mean[b] = sa[b] * rd_;
            float sm = sq[b] * rd_;
            sd[b] = sqrtf(fmaxf(sm - mean[b] * mean[b], 1e-6f));
        }
        const int chunk = n >> 4, nl = n & 15;
        int tA = nl * 4 + par * 2;               // each half writes 2 tasks
        float4 fA, fB;
        fA.x = par ? mean[2] : mean[0]; fA.y = par ? mx[2] : mx[0];
        fA.z = par ? mn[2] : mn[0];     fA.w = par ? sd[2] : sd[0];
        fB.x = par ? mean[3] : mean[1]; fB.y = par ? mx[3] : mx[1];
        fB.z = par ? mn[3] : mn[1];     fB.w = par ? sd[3] : sd[1];
        Fq[(size_t)(chunk * 32 + d) * 64 + tA] = fA;
        Fq[(size_t)(chunk * 32 + d) * 64 + tA + 1] = fB;
    }
}

// ---------------- conv kernel ----------------
// Grid 250 x 1024 (16 waves = 4 waves/SIMD at 1 block/CU). Block owns 5 chunks
// (T=5). Wave w computes outputs {w*2, w*2+1}; lane = task within chunk.
// r8 fix vs r7: NO lambda with array-pointer param (it defeated SROA -> cfA/cfB/y
// demoted to scratch -> 1.7 GB/dispatch of local-memory traffic, 550 us). The
// FMAB macro names the arrays directly; all indices compile-time after unroll.
#define FMAB(CF, JJ) do {                                                      \
    const float4* wp_ = wf + (JJ) * 6;                                         \
    _Pragma("unroll")                                                          \
    for (int f_ = 0; f_ < 4; ++f_) {                                           \
        _Pragma("unroll")                                                      \
        for (int k_ = 0; k_ < 3; ++k_) {                                       \
            int p_ = f_ * 3 + k_;                                              \
            float4 q_ = wp_[p_ >> 1];                                          \
            float wlo_ = (p_ & 1) ? q_.z : q_.x;                               \
            float whi_ = (p_ & 1) ? q_.w : q_.y;                               \
            _Pragma("unroll")                                                  \
            for (int cc_ = 0; cc_ < 5; ++cc_) {                                \
                float cv_ = (&CF[cc_].x)[f_];                                  \
                y[cc_][k_][0] = fmaf(cv_, wlo_, y[cc_][k_][0]);                \
                y[cc_][k_][1] = fmaf(cv_, whi_, y[cc_][k_][1]);                \
            }                                                                  \
        }                                                                      \
    }                                                                          \
} while (0)

__launch_bounds__(1024, 4)
__global__ void k_conv(const float* __restrict__ xin, float* __restrict__ xout,
                       const float4* __restrict__ Fq, const float* __restrict__ pw_l,
                       const float* __restrict__ scale, const float* __restrict__ invs,
                       const float* __restrict__ conv_b_l) {
    __shared__ __align__(16) float4 s_pw[16 * 208];   // 53248 B
    const int tid = threadIdx.x;
    {
        const float4* p4 = (const float4*)pw_l;
        for (int i = tid; i < 16 * 208; i += 1024) s_pw[i] = p4[i];
    }
    const int wq = __builtin_amdgcn_readfirstlane(tid >> 6);   // 0..15
    const int lane = tid & 63;
    const float4* wx = s_pw + wq * 208;       // x-part: 16 quads
    const float4* wf = wx + 16;               // feats: 6 quads per jj
    float bx = conv_b_l[wq * 2], by = conv_b_l[wq * 2 + 1];
    __syncthreads();

    const int set = blockIdx.x;               // chunks set*5 .. set*5+4
    const int nl2 = lane >> 2, b2 = lane & 3;

    float y[5][3][2];
    #pragma unroll
    for (int cc = 0; cc < 5; ++cc) {
        y[cc][0][0] = bx; y[cc][0][1] = by;
        y[cc][1][0] = 0.f; y[cc][1][1] = 0.f;
        y[cc][2][0] = 0.f; y[cc][2][1] = 0.f;
    }

    // ---- x part: K rows 0..31 ([n][d][b] layout -> strided dword loads, L1/L2-hot) ----
    #pragma unroll 2
    for (int jg = 0; jg < 8; ++jg) {
        float cxv[5][4];
        #pragma unroll
        for (int cc = 0; cc < 5; ++cc) {
            int n = (set * 5 + cc) * 16 + nl2;
            const float* xb = xin + (size_t)n * 128 + b2;
            #pragma unroll
            for (int dj = 0; dj < 4; ++dj)
                cxv[cc][dj] = xb[(jg * 4 + dj) * 4];
        }
        #pragma unroll
        for (int dj = 0; dj < 4; ++dj) {
            int j = jg * 4 + dj;
            float4 q = wx[j >> 1];
            float wlo = (j & 1) ? q.z : q.x;
            float whi = (j & 1) ? q.w : q.y;
            #pragma unroll
            for (int cc = 0; cc < 5; ++cc) {
                float cv = cxv[cc][dj];
                y[cc][0][0] = fmaf(cv, wlo, y[cc][0][0]);
                y[cc][0][1] = fmaf(cv, whi, y[cc][0][1]);
            }
        }
    }

    // ---- feats: 32 d-blocks, ping-pong prefetch (direct arrays, no pointer param) ----
    float4 cfA[5], cfB[5];
    #pragma unroll
    for (int cc = 0; cc < 5; ++cc)
        cfA[cc] = Fq[(size_t)((set * 5 + cc) * 32 + 0) * 64 + lane];
    for (int jj = 0; jj < 32; jj += 2) {
        #pragma unroll
        for (int cc = 0; cc < 5; ++cc)
            cfB[cc] = Fq[(size_t)((set * 5 + cc) * 32 + jj + 1) * 64 + lane];
        FMAB(cfA, jj);
        if (jj + 2 < 32) {
            #pragma unroll
            for (int cc = 0; cc < 5; ++cc)
                cfA[cc] = Fq[(size_t)((set * 5 + cc) * 32 + jj + 2) * 64 + lane];
        }
        FMAB(cfB, jj + 1);
    }

    // ---- epilogue: out[n][o][b] scalar stores ----
    #pragma unroll
    for (int cc = 0; cc < 5; ++cc) {
        int n = (set * 5 + cc) * 16 + nl2;
        float scn = scale[n], ivn = invs[n];
        float* xo = xout + (size_t)n * 128 + b2;
        float v0 = fmaxf(0.f, y[cc][0][0] + scn * y[cc][1][0] + ivn * y[cc][2][0]);
        float v1 = fmaxf(0.f, y[cc][0][1] + scn * y[cc][1][1] + ivn * y[cc][2][1]);
        xo[(wq * 2) * 4] = v0;
        xo[(wq * 2 + 1) * 4] = v1;
    }
}

// ---------------- final scoring ----------------
__global__ void k_score(const float* __restrict__ xL, const float* __restrict__ query_emb,
                        const int* __restrict__ r_index, const int* __restrict__ t_index,
                        const float* __restrict__ W1, const float* __restrict__ b1,
                        const float* __restrict__ W2, const float* __restrict__ b2,
                        float* __restrict__ out) {
    int bi = blockIdx.x;            // 0..127
    int b = bi >> 5, kk = bi & 31;
    int j = threadIdx.x;            // 0..63
    __shared__ float sf[64];
    int t = t_index[b * KK + kk];
    float f = (j < DD) ? xL[(size_t)t * 128 + j * 4 + b]
                       : query_emb[r_index[b] * DD + (j - DD)];
    sf[j] = f;
    __syncthreads();
    float acc = b1[j];
    #pragma unroll 8
    for (int i2 = 0; i2 < 64; ++i2) acc = fmaf(sf[i2], W1[j * 64 + i2], acc);
    float h = fmaxf(acc, 0.f);
    float prod = h * W2[j];
    #pragma unroll
    for (int off = 32; off > 0; off >>= 1) prod += __shfl_down(prod, off);
    if (j == 0) out[b * KK + kk] = prod + b2[0];
}

extern "C" void kernel_launch(void* const* d_in, const int* in_sizes, int n_in,
                              void* d_out, int out_size, void* d_ws, size_t ws_size,
                              hipStream_t stream) {
    const int* ei        = (const int*)d_in[0];
    const int* et        = (const int*)d_in[1];
    const int* h_index   = (const int*)d_in[2];
    const int* t_index   = (const int*)d_in[3];
    const int* r_index   = (const int*)d_in[4];
    const float* query_emb = (const float*)d_in[6];
    const float* rel_W   = (const float*)d_in[7];
    const float* rel_b   = (const float*)d_in[8];
    const float* conv_W  = (const float*)d_in[9];
    const float* conv_b  = (const float*)d_in[10];
    const float* W1      = (const float*)d_in[11];
    const float* b1      = (const float*)d_in[12];
    const float* W2      = (const float*)d_in[13];
    const float* b2      = (const float*)d_in[14];

    float* ws = (float*)d_ws;
    float* x0      = ws + OFF_X0;
    float* x1      = ws + OFF_X1;
    int*   row_ptr = (int*)(ws + OFF_RP);
    int*   cursor  = (int*)(ws + OFF_CUR);
    int*   es      = (int*)(ws + OFF_ES);
    float* rdeg    = ws + OFF_DEG;
    float* sc      = ws + OFF_SC;
    float* invs    = ws + OFF_INV;
    int*   bsum    = (int*)(ws + OFF_BS);
    float* blog    = ws + OFF_BL;
    int*   boff    = (int*)(ws + OFF_BO);
    float* meanw   = ws + OFF_MEAN;
    float* rel_all = ws + OFF_REL;
    float* pw      = ws + OFF_PW;
    float4* Fq     = (float4*)(ws + OFF_F);
    float* out     = (float*)d_out;

    // prep
    k_init<<<1024, 256, 0, stream>>>(h_index, r_index, query_emb, x0, cursor);
    k_hist<<<(N_EDGES + 255) / 256, 256, 0, stream>>>(ei, cursor);
    k_part<<<NBLK, 256, 0, stream>>>(cursor, bsum, blog);
    k_scan2<<<1, 128, 0, stream>>>(bsum, blog, boff, meanw);
    k_final<<<NBLK, 256, 0, stream>>>(cursor, row_ptr, boff, meanw, rdeg, sc, invs);
    k_scatter<<<(N_EDGES + 255) / 256, 256, 0, stream>>>(ei, et, cursor, es);
    const int NPREP = LL * BB * RR * DD + LL * 16 * 832;
    k_prep_w<<<(NPREP + 255) / 256, 256, 0, stream>>>(query_emb, r_index, rel_W, rel_b,
                                                      conv_W, rel_all, pw);

    // 4 BF layers, ping-pong x0/x1
    for (int l = 0; l < LL; ++l) {
        const float* xi = (l & 1) ? x1 : x0;
        float* xo = (l & 1) ? x0 : x1;
        k_gather<<<1536, 256, 0, stream>>>(xi, Fq, row_ptr, es,
                                           rel_all + (size_t)l * RR * BB * DD,
                                           rdeg, h_index, r_index, query_emb);
        k_conv<<<250, 1024, 0, stream>>>(xi, xo, Fq, pw + (size_t)l * 16 * 832,
                                         sc, invs, conv_b + l * DD);
    }

    k_score<<<BB * KK, 64, 0, stream>>>(x0, query_emb, r_index, t_index, W1, b1, W2, b2, out);
}

// Round 9
// 329.106 us; speedup vs baseline: 7.0650x; 1.0356x over previous
//
#include <hip/hip_runtime.h>
#include <hip/hip_bf16.h>

// NBFNet Bellman-Ford pass, MI355X. N=20000, E=200000, B=4, K=32, D=32, R=36, L=4.
// x layout: [n][d][b] (b innermost) -> gather reads one dwordx4 per edge per lane.
#define N_NODES 20000
#define N_EDGES 200000
#define BB 4
#define KK 32
#define DD 32
#define RR 36
#define LL 4
#define NCHUNKS (N_NODES / 16)   // 1250 = 250 * 5
#define NBLK 79                  // ceil(20000/256)

// ---------------- ws layout (element offsets, 4B units) ----------------
constexpr size_t OFF_X0   = 0;                                        // float[N*D*B], x[(n*32+d)*4+b]
constexpr size_t OFF_X1   = OFF_X0 + (size_t)BB * N_NODES * DD;
constexpr size_t OFF_RP   = OFF_X1 + (size_t)BB * N_NODES * DD;       // int[N+1]
constexpr size_t OFF_CUR  = OFF_RP + 20032;                           // int[N]
constexpr size_t OFF_ES   = OFF_CUR + N_NODES;                        // int[E] src | type<<16
constexpr size_t OFF_DEG  = OFF_ES + N_EDGES;                         // float[N] 1/deg
constexpr size_t OFF_SC   = OFF_DEG + N_NODES;                        // float[N] scale
constexpr size_t OFF_INV  = OFF_SC + N_NODES;                         // float[N] 1/max(scale,.01)
constexpr size_t OFF_BS   = OFF_INV + N_NODES;                        // int[128] block sums
constexpr size_t OFF_BL   = OFF_BS + 128;                             // float[128] block log sums
constexpr size_t OFF_BO   = OFF_BL + 128;                             // int[128] block offsets
constexpr size_t OFF_MEAN = OFF_BO + 128;                             // float[16]
constexpr size_t OFF_REL  = OFF_MEAN + 16;                            // float[L*R*D*B] [l][ty][d][b]
constexpr size_t OFF_PW   = OFF_REL + (size_t)LL * RR * BB * DD;      // float[L*16*832]
constexpr size_t OFF_F    = OFF_PW + (size_t)LL * 16 * 832;           // float4[(NCHUNKS*32+64)*64]
// NOTE: Fq has 64 rows (64*64 float4) of slack: the distance-3 pipeline reads
// up to 3 rows past the last chunk's tile.

// ---------------- prep kernels ----------------

__global__ void k_init(const int* __restrict__ h_index, const int* __restrict__ r_index,
                       const float* __restrict__ query_emb, float* __restrict__ x0,
                       int* __restrict__ cursor) {
    int i = blockIdx.x * blockDim.x + threadIdx.x;
    int stride = gridDim.x * blockDim.x;
    for (int t = i; t < N_NODES; t += stride) cursor[t] = 0;
    for (int t = i; t < BB * N_NODES * DD; t += stride) {
        int b = t & 3; int d = (t >> 2) & 31; int n = t >> 7;
        float v = 0.f;
        if (n == h_index[b]) v = query_emb[r_index[b] * DD + d];
        x0[t] = v;
    }
}

__global__ void k_hist(const int* __restrict__ ei, int* __restrict__ cursor) {
    int e = blockIdx.x * blockDim.x + threadIdx.x;
    if (e < N_EDGES) atomicAdd(&cursor[ei[N_EDGES + e]], 1);
}

// per-block partial sums of deg histogram + log(deg)
__global__ void k_part(const int* __restrict__ cursor, int* __restrict__ bsum,
                       float* __restrict__ blog) {
    __shared__ int si[256];
    __shared__ float sf2[256];
    int tid = threadIdx.x;
    int i = blockIdx.x * 256 + tid;
    int v = (i < N_NODES) ? cursor[i] : 0;
    float lg = (i < N_NODES) ? logf((float)(v + 1)) : 0.f;
    si[tid] = v; sf2[tid] = lg;
    __syncthreads();
    for (int off = 128; off > 0; off >>= 1) {
        if (tid < off) { si[tid] += si[tid + off]; sf2[tid] += sf2[tid + off]; }
        __syncthreads();
    }
    if (tid == 0) { bsum[blockIdx.x] = si[0]; blog[blockIdx.x] = sf2[0]; }
}

// single small block: scan the 79 block sums; total log -> mean
__global__ void k_scan2(const int* __restrict__ bsum, const float* __restrict__ blog,
                        int* __restrict__ boff, float* __restrict__ meanw) {
    __shared__ int si[128];
    __shared__ float sf2[128];
    int t = threadIdx.x;
    int v = (t < NBLK) ? bsum[t] : 0;
    float lg = (t < NBLK) ? blog[t] : 0.f;
    si[t] = v; sf2[t] = lg;
    __syncthreads();
    for (int off = 1; off < 128; off <<= 1) {
        int tv = (t >= off) ? si[t - off] : 0;
        float tf = (t >= off) ? sf2[t - off] : 0.f;
        __syncthreads();
        si[t] += tv; sf2[t] += tf;
        __syncthreads();
    }
    if (t < NBLK) boff[t] = si[t] - v;                      // exclusive
    if (t == 127) meanw[0] = sf2[127] / (float)N_NODES;     // mean(log deg)
}

// per-block scan + global offset -> row_ptr/cursor; rdeg/scale/inv
__global__ void k_final(int* __restrict__ cursor, int* __restrict__ row_ptr,
                        const int* __restrict__ boff, const float* __restrict__ meanw,
                        float* __restrict__ rdeg, float* __restrict__ scale,
                        float* __restrict__ invs) {
    __shared__ int si[256];
    int tid = threadIdx.x;
    int i = blockIdx.x * 256 + tid;
    int v = (i < N_NODES) ? cursor[i] : 0;
    si[tid] = v;
    __syncthreads();
    for (int off = 1; off < 256; off <<= 1) {
        int tv = (tid >= off) ? si[tid - off] : 0;
        __syncthreads();
        si[tid] += tv;
        __syncthreads();
    }
    int rp = boff[blockIdx.x] + si[tid] - v;   // exclusive prefix
    if (i < N_NODES) {
        row_ptr[i] = rp;
        cursor[i] = rp;
        float dg = (float)(v + 1);
        float sc = logf(dg) / meanw[0];
        rdeg[i] = 1.f / dg;
        scale[i] = sc;
        invs[i] = 1.f / fmaxf(sc, 0.01f);
    }
    if (i == 0) row_ptr[N_NODES] = N_EDGES;
}

__global__ void k_scatter(const int* __restrict__ ei, const int* __restrict__ et,
                          int* __restrict__ cursor, int* __restrict__ es) {
    int e = blockIdx.x * blockDim.x + threadIdx.x;
    if (e < N_EDGES) {
        int dnode = ei[N_EDGES + e];
        int p = atomicAdd(&cursor[dnode], 1);
        es[p] = ei[e] | (et[e] << 16);
    }
}

// rel tables [l][ty][d][b] + prepped conv weights.
// pw layout per (l, w), w in [0,16) covering outputs o = {w*2, w*2+1}:
//   r in [0,64):  x-part.  j = r>>1, o = w*2 + (r&1), col = j
//   r in [64,832): feats.  r2=r-64; jj=r2/24; rem=r2%24; p=rem>>1 (=f*3+k);
//                  o = w*2 + (rem&1); col = 32 + (jj*4 + p/3)*3 + p%3
__global__ void k_prep_w(const float* __restrict__ query_emb, const int* __restrict__ r_index,
                         const float* __restrict__ rel_W, const float* __restrict__ rel_b,
                         const float* __restrict__ conv_W,
                         float* __restrict__ rel_all, float* __restrict__ pw) {
    int i = blockIdx.x * blockDim.x + threadIdx.x;
    const int NREL = LL * BB * RR * DD;
    if (i < NREL) {
        int d = i & 31;
        int ty = (i >> 5) % RR;
        int b = (i / (32 * RR)) & 3;
        int l = i / (32 * RR * BB);
        const float* q = query_emb + r_index[b] * DD;
        const float* w = rel_W + ((size_t)l * RR * DD + ty * DD + d) * DD;
        float acc = rel_b[l * RR * DD + ty * DD + d];
        #pragma unroll
        for (int k2 = 0; k2 < DD; ++k2) acc = fmaf(q[k2], w[k2], acc);
        rel_all[(((size_t)l * RR + ty) * DD + d) * BB + b] = acc;
    } else {
        int i2 = i - NREL;
        if (i2 >= LL * 16 * 832) return;
        int r = i2 % 832; int lw = i2 / 832;
        int w = lw & 15, l = lw >> 4;
        int o, col;
        if (r < 64) { col = r >> 1; o = w * 2 + (r & 1); }
        else {
            int r2 = r - 64;
            int jj = r2 / 24, rem = r2 % 24;
            int p = rem >> 1;
            o = w * 2 + (rem & 1);
            col = DD + (jj * 4 + p / 3) * 3 + (p % 3);
        }
        pw[i2] = conv_W[(size_t)(l * DD + o) * (13 * DD) + col];
    }
}

// ---------------- gather + PNA kernel ----------------
// Wave per node (grid-stride). lane = d + 32*par; parity halves process alternate
// edges (4-deep unroll = 8 x-row dwordx4 loads in flight per wave); shfl_xor(32) combine.
// Writes F transposed: Fq[(chunk*32 + d)*64 + task] = {mean,max,min,std}.
__launch_bounds__(256, 6)
__global__ void k_gather(const float* __restrict__ xin, float4* __restrict__ Fq,
                         const int* __restrict__ row_ptr, const int* __restrict__ es,
                         const float* __restrict__ rel_l, const float* __restrict__ rdeg,
                         const int* __restrict__ h_index, const int* __restrict__ r_index,
                         const float* __restrict__ query_emb) {
    __shared__ __align__(16) float s_rel[RR * BB * DD];   // 18432 B, [ty][d][b]
    const int tid = threadIdx.x;
    {   // stage rel table once per block
        const float4* p4 = (const float4*)rel_l;
        float4* s4 = (float4*)s_rel;
        for (int i = tid; i < RR * BB * DD / 4; i += 256) s4[i] = p4[i];
    }
    const int lane = tid & 63;
    const int d = lane & 31;
    const int par = lane >> 5;
    int hb[4]; float qv[4];
    #pragma unroll
    for (int b = 0; b < 4; ++b) {
        hb[b] = h_index[b];
        qv[b] = query_emb[r_index[b] * DD + d];
    }
    __syncthreads();

    const int nwaves = gridDim.x * 4;
    for (int n = blockIdx.x * 4 + (tid >> 6); n < N_NODES; n += nwaves) {
        float sa[4], sq[4], mx[4], mn[4];
        #pragma unroll
        for (int b = 0; b < 4; ++b) {
            float bv = (n == hb[b]) ? qv[b] : 0.f;
            float bs = par ? 0.f : bv;        // count boundary message once in sum/sq
            sa[b] = bs; sq[b] = bs * bv; mx[b] = bv; mn[b] = bv;
        }
        auto proc = [&](int ee) {
            int pk = es[ee];
            float4 xv = *(const float4*)(xin + ((size_t)(pk & 0xFFFF) * DD + d) * 4);
            float4 rv = *(const float4*)(s_rel + (((pk >> 16) * DD) + d) * 4);
            #pragma unroll
            for (int b = 0; b < 4; ++b) {
                float m = (&xv.x)[b] * (&rv.x)[b];
                sa[b] += m; sq[b] = fmaf(m, m, sq[b]);
                mx[b] = fmaxf(mx[b], m); mn[b] = fminf(mn[b], m);
            }
        };
        int e0 = row_ptr[n], e1 = row_ptr[n + 1];
        int e = e0 + par;                        // parity-strided: 2 edges per step
        for (; e + 6 < e1; e += 8) { proc(e); proc(e + 2); proc(e + 4); proc(e + 6); }
        for (; e < e1; e += 2) proc(e);
        #pragma unroll
        for (int b = 0; b < 4; ++b) {
            sa[b] += __shfl_xor(sa[b], 32);
            sq[b] += __shfl_xor(sq[b], 32);
            mx[b] = fmaxf(mx[b], __shfl_xor(mx[b], 32));
            mn[b] = fminf(mn[b], __shfl_xor(mn[b], 32));
        }
        float rd_ = rdeg[n];
        float mean[4], sd[4];
        #pragma unroll
        for (int b = 0; b < 4; ++b) {
            mean[b] = sa[b] * rd_;
            float sm = sq[b] * rd_;
            sd[b] = sqrtf(fmaxf(sm - mean[b] * mean[b], 1e-6f));
        }
        const int chunk = n >> 4, nl = n & 15;
        int tA = nl * 4 + par * 2;               // each half writes 2 tasks
        float4 fA, fB;
        fA.x = par ? mean[2] : mean[0]; fA.y = par ? mx[2] : mx[0];
        fA.z = par ? mn[2] : mn[0];     fA.w = par ? sd[2] : sd[0];
        fB.x = par ? mean[3] : mean[1]; fB.y = par ? mx[3] : mx[1];
        fB.z = par ? mn[3] : mn[1];     fB.w = par ? sd[3] : sd[1];
        Fq[(size_t)(chunk * 32 + d) * 64 + tA] = fA;
        Fq[(size_t)(chunk * 32 + d) * 64 + tA + 1] = fB;
    }
}

// ---------------- conv kernel ----------------
// Grid 250 x 1024 (16 waves = 4 waves/SIMD at 1 block/CU). Block owns 5 chunks
// (T=5). Wave w computes outputs {w*2, w*2+1}; lane = task within chunk.
// r9: distance-3 software pipeline on Fq loads (4 rotating statically-named
// buffers cf0..cf3, unroll-4 body). r8's ping-pong had only 1-FMAB (~240
// wave-cyc) cover vs ~500-900 cyc Fq latency -> all 4 waves stalled together
// (wall = sum of pipe times). 3-FMAB cover (~720+ wave-cyc) hides it.
#define FMAB(CF, JJ) do {                                                      \
    const float4* wp_ = wf + (JJ) * 6;                                         \
    _Pragma("unroll")                                                          \
    for (int f_ = 0; f_ < 4; ++f_) {                                           \
        _Pragma("unroll")                                                      \
        for (int k_ = 0; k_ < 3; ++k_) {                                       \
            int p_ = f_ * 3 + k_;                                              \
            float4 q_ = wp_[p_ >> 1];                                          \
            float wlo_ = (p_ & 1) ? q_.z : q_.x;                               \
            float whi_ = (p_ & 1) ? q_.w : q_.y;                               \
            _Pragma("unroll")                                                  \
            for (int cc_ = 0; cc_ < 5; ++cc_) {                                \
                float cv_ = (&CF[cc_].x)[f_];                                  \
                y[cc_][k_][0] = fmaf(cv_, wlo_, y[cc_][k_][0]);                \
                y[cc_][k_][1] = fmaf(cv_, whi_, y[cc_][k_][1]);                \
            }                                                                  \
        }                                                                      \
    }                                                                          \
} while (0)

#define LOADCF(CF, ROW) do {                                                   \
    _Pragma("unroll")                                                          \
    for (int cc_ = 0; cc_ < 5; ++cc_)                                          \
        CF[cc_] = Fq[(size_t)((set * 5 + cc_) * 32 + (ROW)) * 64 + lane];      \
} while (0)

__launch_bounds__(1024, 4)
__global__ void k_conv(const float* __restrict__ xin, float* __restrict__ xout,
                       const float4* __restrict__ Fq, const float* __restrict__ pw_l,
                       const float* __restrict__ scale, const float* __restrict__ invs,
                       const float* __restrict__ conv_b_l) {
    __shared__ __align__(16) float4 s_pw[16 * 208];   // 53248 B
    const int tid = threadIdx.x;
    {
        const float4* p4 = (const float4*)pw_l;
        for (int i = tid; i < 16 * 208; i += 1024) s_pw[i] = p4[i];
    }
    const int wq = __builtin_amdgcn_readfirstlane(tid >> 6);   // 0..15
    const int lane = tid & 63;
    const float4* wx = s_pw + wq * 208;       // x-part: 16 quads
    const float4* wf = wx + 16;               // feats: 6 quads per jj
    float bx = conv_b_l[wq * 2], by = conv_b_l[wq * 2 + 1];
    __syncthreads();

    const int set = blockIdx.x;               // chunks set*5 .. set*5+4
    const int nl2 = lane >> 2, b2 = lane & 3;

    float y[5][3][2];
    #pragma unroll
    for (int cc = 0; cc < 5; ++cc) {
        y[cc][0][0] = bx; y[cc][0][1] = by;
        y[cc][1][0] = 0.f; y[cc][1][1] = 0.f;
        y[cc][2][0] = 0.f; y[cc][2][1] = 0.f;
    }

    // ---- x part: K rows 0..31 ([n][d][b] layout -> strided dword loads, L1/L2-hot) ----
    #pragma unroll 2
    for (int jg = 0; jg < 8; ++jg) {
        float cxv[5][4];
        #pragma unroll
        for (int cc = 0; cc < 5; ++cc) {
            int n = (set * 5 + cc) * 16 + nl2;
            const float* xb = xin + (size_t)n * 128 + b2;
            #pragma unroll
            for (int dj = 0; dj < 4; ++dj)
                cxv[cc][dj] = xb[(jg * 4 + dj) * 4];
        }
        #pragma unroll
        for (int dj = 0; dj < 4; ++dj) {
            int j = jg * 4 + dj;
            float4 q = wx[j >> 1];
            float wlo = (j & 1) ? q.z : q.x;
            float whi = (j & 1) ? q.w : q.y;
            #pragma unroll
            for (int cc = 0; cc < 5; ++cc) {
                float cv = cxv[cc][dj];
                y[cc][0][0] = fmaf(cv, wlo, y[cc][0][0]);
                y[cc][0][1] = fmaf(cv, whi, y[cc][0][1]);
            }
        }
    }

    // ---- feats: 32 d-blocks, distance-3 pipeline over 4 static buffers ----
    float4 cf0[5], cf1[5], cf2[5], cf3[5];
    LOADCF(cf0, 0);
    LOADCF(cf1, 1);
    LOADCF(cf2, 2);
    #pragma unroll 1
    for (int jj = 0; jj < 32; jj += 4) {
        LOADCF(cf3, jj + 3); FMAB(cf0, jj);
        LOADCF(cf0, jj + 4); FMAB(cf1, jj + 1);   // rows 32..34 read slack (harmless)
        LOADCF(cf1, jj + 5); FMAB(cf2, jj + 2);
        LOADCF(cf2, jj + 6); FMAB(cf3, jj + 3);
    }

    // ---- epilogue: out[n][o][b] scalar stores ----
    #pragma unroll
    for (int cc = 0; cc < 5; ++cc) {
        int n = (set * 5 + cc) * 16 + nl2;
        float scn = scale[n], ivn = invs[n];
        float* xo = xout + (size_t)n * 128 + b2;
        float v0 = fmaxf(0.f, y[cc][0][0] + scn * y[cc][1][0] + ivn * y[cc][2][0]);
        float v1 = fmaxf(0.f, y[cc][0][1] + scn * y[cc][1][1] + ivn * y[cc][2][1]);
        xo[(wq * 2) * 4] = v0;
        xo[(wq * 2 + 1) * 4] = v1;
    }
}

// ---------------- final scoring ----------------
__global__ void k_score(const float* __restrict__ xL, const float* __restrict__ query_emb,
                        const int* __restrict__ r_index, const int* __restrict__ t_index,
                        const float* __restrict__ W1, const float* __restrict__ b1,
                        const float* __restrict__ W2, const float* __restrict__ b2,
                        float* __restrict__ out) {
    int bi = blockIdx.x;            // 0..127
    int b = bi >> 5, kk = bi & 31;
    int j = threadIdx.x;            // 0..63
    __shared__ float sf[64];
    int t = t_index[b * KK + kk];
    float f = (j < DD) ? xL[(size_t)t * 128 + j * 4 + b]
                       : query_emb[r_index[b] * DD + (j - DD)];
    sf[j] = f;
    __syncthreads();
    float acc = b1[j];
    #pragma unroll 8
    for (int i2 = 0; i2 < 64; ++i2) acc = fmaf(sf[i2], W1[j * 64 + i2], acc);
    float h = fmaxf(acc, 0.f);
    float prod = h * W2[j];
    #pragma unroll
    for (int off = 32; off > 0; off >>= 1) prod += __shfl_down(prod, off);
    if (j == 0) out[b * KK + kk] = prod + b2[0];
}

extern "C" void kernel_launch(void* const* d_in, const int* in_sizes, int n_in,
                              void* d_out, int out_size, void* d_ws, size_t ws_size,
                              hipStream_t stream) {
    const int* ei        = (const int*)d_in[0];
    const int* et        = (const int*)d_in[1];
    const int* h_index   = (const int*)d_in[2];
    const int* t_index   = (const int*)d_in[3];
    const int* r_index   = (const int*)d_in[4];
    const float* query_emb = (const float*)d_in[6];
    const float* rel_W   = (const float*)d_in[7];
    const float* rel_b   = (const float*)d_in[8];
    const float* conv_W  = (const float*)d_in[9];
    const float* conv_b  = (const float*)d_in[10];
    const float* W1      = (const float*)d_in[11];
    const float* b1      = (const float*)d_in[12];
    const float* W2      = (const float*)d_in[13];
    const float* b2      = (const float*)d_in[14];

    float* ws = (float*)d_ws;
    float* x0      = ws + OFF_X0;
    float* x1      = ws + OFF_X1;
    int*   row_ptr = (int*)(ws + OFF_RP);
    int*   cursor  = (int*)(ws + OFF_CUR);
    int*   es      = (int*)(ws + OFF_ES);
    float* rdeg    = ws + OFF_DEG;
    float* sc      = ws + OFF_SC;
    float* invs    = ws + OFF_INV;
    int*   bsum    = (int*)(ws + OFF_BS);
    float* blog    = ws + OFF_BL;
    int*   boff    = (int*)(ws + OFF_BO);
    float* meanw   = ws + OFF_MEAN;
    float* rel_all = ws + OFF_REL;
    float* pw      = ws + OFF_PW;
    float4* Fq     = (float4*)(ws + OFF_F);
    float* out     = (float*)d_out;

    // prep
    k_init<<<1024, 256, 0, stream>>>(h_index, r_index, query_emb, x0, cursor);
    k_hist<<<(N_EDGES + 255) / 256, 256, 0, stream>>>(ei, cursor);
    k_part<<<NBLK, 256, 0, stream>>>(cursor, bsum, blog);
    k_scan2<<<1, 128, 0, stream>>>(bsum, blog, boff, meanw);
    k_final<<<NBLK, 256, 0, stream>>>(cursor, row_ptr, boff, meanw, rdeg, sc, invs);
    k_scatter<<<(N_EDGES + 255) / 256, 256, 0, stream>>>(ei, et, cursor, es);
    const int NPREP = LL * BB * RR * DD + LL * 16 * 832;
    k_prep_w<<<(NPREP + 255) / 256, 256, 0, stream>>>(query_emb, r_index, rel_W, rel_b,
                                                      conv_W, rel_all, pw);

    // 4 BF layers, ping-pong x0/x1
    for (int l = 0; l < LL; ++l) {
        const float* xi = (l & 1) ? x1 : x0;
        float* xo = (l & 1) ? x0 : x1;
        k_gather<<<1536, 256, 0, stream>>>(xi, Fq, row_ptr, es,
                                           rel_all + (size_t)l * RR * BB * DD,
                                           rdeg, h_index, r_index, query_emb);
        k_conv<<<250, 1024, 0, stream>>>(xi, xo, Fq, pw + (size_t)l * 16 * 832,
                                         sc, invs, conv_b + l * DD);
    }

    k_score<<<BB * KK, 64, 0, stream>>>(x0, query_emb, r_index, t_index, W1, b1, W2, b2, out);
}

// Round 10
// 322.721 us; speedup vs baseline: 7.2048x; 1.0198x over previous
//
#include <hip/hip_runtime.h>
#include <hip/hip_bf16.h>

// NBFNet Bellman-Ford pass, MI355X. N=20000, E=200000, B=4, K=32, D=32, R=36, L=4.
// x layout: [n][d][b] (b innermost) -> gather reads one dwordx4 per edge per lane.
#define N_NODES 20000
#define N_EDGES 200000
#define BB 4
#define KK 32
#define DD 32
#define RR 36
#define LL 4
#define NCHUNKS (N_NODES / 16)   // 1250 = 250 * 5
#define NBLK 79                  // ceil(20000/256)

// ---------------- ws layout (element offsets, 4B units) ----------------
constexpr size_t OFF_X0   = 0;                                        // float[N*D*B], x[(n*32+d)*4+b]
constexpr size_t OFF_X1   = OFF_X0 + (size_t)BB * N_NODES * DD;
constexpr size_t OFF_RP   = OFF_X1 + (size_t)BB * N_NODES * DD;       // int[N+1]
constexpr size_t OFF_CUR  = OFF_RP + 20032;                           // int[N]
constexpr size_t OFF_ES   = OFF_CUR + N_NODES;                        // int[E] src | type<<16
constexpr size_t OFF_DEG  = OFF_ES + N_EDGES;                         // float[N] 1/deg
constexpr size_t OFF_SC   = OFF_DEG + N_NODES;                        // float[N] scale
constexpr size_t OFF_INV  = OFF_SC + N_NODES;                         // float[N] 1/max(scale,.01)
constexpr size_t OFF_BS   = OFF_INV + N_NODES;                        // int[128] block sums
constexpr size_t OFF_BL   = OFF_BS + 128;                             // float[128] block log sums
constexpr size_t OFF_BO   = OFF_BL + 128;                             // int[128] block offsets
constexpr size_t OFF_MEAN = OFF_BO + 128;                             // float[16]
constexpr size_t OFF_REL  = OFF_MEAN + 16;                            // float[L*R*D*B] [l][ty][d][b]
constexpr size_t OFF_PW   = OFF_REL + (size_t)LL * RR * BB * DD;      // float[L*16*832]
constexpr size_t OFF_F    = OFF_PW + (size_t)LL * 16 * 832;           // float4[(NCHUNKS*32+64)*64]
// NOTE: Fq has 64 rows (64*64 float4) of slack: the distance-3 pipeline reads
// up to 3 rows past the last chunk's tile.

// ---------------- prep kernels ----------------

__global__ void k_init(const int* __restrict__ h_index, const int* __restrict__ r_index,
                       const float* __restrict__ query_emb, float* __restrict__ x0,
                       int* __restrict__ cursor) {
    int i = blockIdx.x * blockDim.x + threadIdx.x;
    int stride = gridDim.x * blockDim.x;
    for (int t = i; t < N_NODES; t += stride) cursor[t] = 0;
    for (int t = i; t < BB * N_NODES * DD; t += stride) {
        int b = t & 3; int d = (t >> 2) & 31; int n = t >> 7;
        float v = 0.f;
        if (n == h_index[b]) v = query_emb[r_index[b] * DD + d];
        x0[t] = v;
    }
}

__global__ void k_hist(const int* __restrict__ ei, int* __restrict__ cursor) {
    int e = blockIdx.x * blockDim.x + threadIdx.x;
    if (e < N_EDGES) atomicAdd(&cursor[ei[N_EDGES + e]], 1);
}

// per-block partial sums of deg histogram + log(deg)
__global__ void k_part(const int* __restrict__ cursor, int* __restrict__ bsum,
                       float* __restrict__ blog) {
    __shared__ int si[256];
    __shared__ float sf2[256];
    int tid = threadIdx.x;
    int i = blockIdx.x * 256 + tid;
    int v = (i < N_NODES) ? cursor[i] : 0;
    float lg = (i < N_NODES) ? logf((float)(v + 1)) : 0.f;
    si[tid] = v; sf2[tid] = lg;
    __syncthreads();
    for (int off = 128; off > 0; off >>= 1) {
        if (tid < off) { si[tid] += si[tid + off]; sf2[tid] += sf2[tid + off]; }
        __syncthreads();
    }
    if (tid == 0) { bsum[blockIdx.x] = si[0]; blog[blockIdx.x] = sf2[0]; }
}

// single small block: scan the 79 block sums; total log -> mean
__global__ void k_scan2(const int* __restrict__ bsum, const float* __restrict__ blog,
                        int* __restrict__ boff, float* __restrict__ meanw) {
    __shared__ int si[128];
    __shared__ float sf2[128];
    int t = threadIdx.x;
    int v = (t < NBLK) ? bsum[t] : 0;
    float lg = (t < NBLK) ? blog[t] : 0.f;
    si[t] = v; sf2[t] = lg;
    __syncthreads();
    for (int off = 1; off < 128; off <<= 1) {
        int tv = (t >= off) ? si[t - off] : 0;
        float tf = (t >= off) ? sf2[t - off] : 0.f;
        __syncthreads();
        si[t] += tv; sf2[t] += tf;
        __syncthreads();
    }
    if (t < NBLK) boff[t] = si[t] - v;                      // exclusive
    if (t == 127) meanw[0] = sf2[127] / (float)N_NODES;     // mean(log deg)
}

// per-block scan + global offset -> row_ptr/cursor; rdeg/scale/inv
__global__ void k_final(int* __restrict__ cursor, int* __restrict__ row_ptr,
                        const int* __restrict__ boff, const float* __restrict__ meanw,
                        float* __restrict__ rdeg, float* __restrict__ scale,
                        float* __restrict__ invs) {
    __shared__ int si[256];
    int tid = threadIdx.x;
    int i = blockIdx.x * 256 + tid;
    int v = (i < N_NODES) ? cursor[i] : 0;
    si[tid] = v;
    __syncthreads();
    for (int off = 1; off < 256; off <<= 1) {
        int tv = (tid >= off) ? si[tid - off] : 0;
        __syncthreads();
        si[tid] += tv;
        __syncthreads();
    }
    int rp = boff[blockIdx.x] + si[tid] - v;   // exclusive prefix
    if (i < N_NODES) {
        row_ptr[i] = rp;
        cursor[i] = rp;
        float dg = (float)(v + 1);
        float sc = logf(dg) / meanw[0];
        rdeg[i] = 1.f / dg;
        scale[i] = sc;
        invs[i] = 1.f / fmaxf(sc, 0.01f);
    }
    if (i == 0) row_ptr[N_NODES] = N_EDGES;
}

__global__ void k_scatter(const int* __restrict__ ei, const int* __restrict__ et,
                          int* __restrict__ cursor, int* __restrict__ es) {
    int e = blockIdx.x * blockDim.x + threadIdx.x;
    if (e < N_EDGES) {
        int dnode = ei[N_EDGES + e];
        int p = atomicAdd(&cursor[dnode], 1);
        es[p] = ei[e] | (et[e] << 16);
    }
}

// rel tables [l][ty][d][b] + prepped conv weights.
// pw layout per (l, w), w in [0,16) covering outputs o = {w*2, w*2+1} (832 floats):
//   r in [0,64):  x-part.  j = r>>1, o = w*2 + (r&1)  -> float idx 2*j + oo
//   r in [64,832): feats.  r2=r-64; jj=r2/24; rem=r2%24; p=rem>>1 (=f*3+k);
//                  o = w*2 + (rem&1) -> float idx 64 + jj*24 + p*2 + oo
__global__ void k_prep_w(const float* __restrict__ query_emb, const int* __restrict__ r_index,
                         const float* __restrict__ rel_W, const float* __restrict__ rel_b,
                         const float* __restrict__ conv_W,
                         float* __restrict__ rel_all, float* __restrict__ pw) {
    int i = blockIdx.x * blockDim.x + threadIdx.x;
    const int NREL = LL * BB * RR * DD;
    if (i < NREL) {
        int d = i & 31;
        int ty = (i >> 5) % RR;
        int b = (i / (32 * RR)) & 3;
        int l = i / (32 * RR * BB);
        const float* q = query_emb + r_index[b] * DD;
        const float* w = rel_W + ((size_t)l * RR * DD + ty * DD + d) * DD;
        float acc = rel_b[l * RR * DD + ty * DD + d];
        #pragma unroll
        for (int k2 = 0; k2 < DD; ++k2) acc = fmaf(q[k2], w[k2], acc);
        rel_all[(((size_t)l * RR + ty) * DD + d) * BB + b] = acc;
    } else {
        int i2 = i - NREL;
        if (i2 >= LL * 16 * 832) return;
        int r = i2 % 832; int lw = i2 / 832;
        int w = lw & 15, l = lw >> 4;
        int o, col;
        if (r < 64) { col = r >> 1; o = w * 2 + (r & 1); }
        else {
            int r2 = r - 64;
            int jj = r2 / 24, rem = r2 % 24;
            int p = rem >> 1;
            o = w * 2 + (rem & 1);
            col = DD + (jj * 4 + p / 3) * 3 + (p % 3);
        }
        pw[i2] = conv_W[(size_t)(l * DD + o) * (13 * DD) + col];
    }
}

// ---------------- gather + PNA kernel ----------------
// Wave per node (grid-stride). lane = d + 32*par; parity halves process alternate
// edges (4-deep unroll = 8 x-row dwordx4 loads in flight per wave); shfl_xor(32) combine.
// Writes F transposed: Fq[(chunk*32 + d)*64 + task] = {mean,max,min,std}.
__launch_bounds__(256, 6)
__global__ void k_gather(const float* __restrict__ xin, float4* __restrict__ Fq,
                         const int* __restrict__ row_ptr, const int* __restrict__ es,
                         const float* __restrict__ rel_l, const float* __restrict__ rdeg,
                         const int* __restrict__ h_index, const int* __restrict__ r_index,
                         const float* __restrict__ query_emb) {
    __shared__ __align__(16) float s_rel[RR * BB * DD];   // 18432 B, [ty][d][b]
    const int tid = threadIdx.x;
    {   // stage rel table once per block
        const float4* p4 = (const float4*)rel_l;
        float4* s4 = (float4*)s_rel;
        for (int i = tid; i < RR * BB * DD / 4; i += 256) s4[i] = p4[i];
    }
    const int lane = tid & 63;
    const int d = lane & 31;
    const int par = lane >> 5;
    int hb[4]; float qv[4];
    #pragma unroll
    for (int b = 0; b < 4; ++b) {
        hb[b] = h_index[b];
        qv[b] = query_emb[r_index[b] * DD + d];
    }
    __syncthreads();

    const int nwaves = gridDim.x * 4;
    for (int n = blockIdx.x * 4 + (tid >> 6); n < N_NODES; n += nwaves) {
        float sa[4], sq[4], mx[4], mn[4];
        #pragma unroll
        for (int b = 0; b < 4; ++b) {
            float bv = (n == hb[b]) ? qv[b] : 0.f;
            float bs = par ? 0.f : bv;        // count boundary message once in sum/sq
            sa[b] = bs; sq[b] = bs * bv; mx[b] = bv; mn[b] = bv;
        }
        auto proc = [&](int ee) {
            int pk = es[ee];
            float4 xv = *(const float4*)(xin + ((size_t)(pk & 0xFFFF) * DD + d) * 4);
            float4 rv = *(const float4*)(s_rel + (((pk >> 16) * DD) + d) * 4);
            #pragma unroll
            for (int b = 0; b < 4; ++b) {
                float m = (&xv.x)[b] * (&rv.x)[b];
                sa[b] += m; sq[b] = fmaf(m, m, sq[b]);
                mx[b] = fmaxf(mx[b], m); mn[b] = fminf(mn[b], m);
            }
        };
        int e0 = row_ptr[n], e1 = row_ptr[n + 1];
        int e = e0 + par;                        // parity-strided: 2 edges per step
        for (; e + 6 < e1; e += 8) { proc(e); proc(e + 2); proc(e + 4); proc(e + 6); }
        for (; e < e1; e += 2) proc(e);
        #pragma unroll
        for (int b = 0; b < 4; ++b) {
            sa[b] += __shfl_xor(sa[b], 32);
            sq[b] += __shfl_xor(sq[b], 32);
            mx[b] = fmaxf(mx[b], __shfl_xor(mx[b], 32));
            mn[b] = fminf(mn[b], __shfl_xor(mn[b], 32));
        }
        float rd_ = rdeg[n];
        float mean[4], sd[4];
        #pragma unroll
        for (int b = 0; b < 4; ++b) {
            mean[b] = sa[b] * rd_;
            float sm = sq[b] * rd_;
            sd[b] = sqrtf(fmaxf(sm - mean[b] * mean[b], 1e-6f));
        }
        const int chunk = n >> 4, nl = n & 15;
        int tA = nl * 4 + par * 2;               // each half writes 2 tasks
        float4 fA, fB;
        fA.x = par ? mean[2] : mean[0]; fA.y = par ? mx[2] : mx[0];
        fA.z = par ? mn[2] : mn[0];     fA.w = par ? sd[2] : sd[0];
        fB.x = par ? mean[3] : mean[1]; fB.y = par ? mx[3] : mx[1];
        fB.z = par ? mn[3] : mn[1];     fB.w = par ? sd[3] : sd[1];
        Fq[(size_t)(chunk * 32 + d) * 64 + tA] = fA;
        Fq[(size_t)(chunk * 32 + d) * 64 + tA + 1] = fB;
    }
}

// ---------------- conv kernel ----------------
// Grid 250 x 1024 (16 waves, 4 waves/SIMD, 1 block/CU). Block owns 5 chunks (T=5).
// Wave w: outputs {w*2, w*2+1}; lane = task within chunk.
// r10: weights via the SCALAR path. r9's three per-CU pipes (TCP ~1280 +
// LDS-weights ~1150 + VALU ~960 cyc per jj-sub-step) ran as a SUM (~3750).
// Weights are wave-uniform -> read through s_load/K$ (uniform pointer +
// compile-time indices), FMAs take the weight as an SGPR operand. The LDS pipe
// term disappears entirely; no conv LDS, no staging barrier. Unlike r2's
// scalar-path failure (13KB re-streamed per chunk, no FMA cover), each 24-float
// uniform group here covers a 240-cycle FMA block and is reused T=5 times.
#define FMAB(CF, JJ) do {                                                      \
    _Pragma("unroll")                                                          \
    for (int p_ = 0; p_ < 12; ++p_) {                                          \
        const int f_ = p_ / 3, k_ = p_ % 3;                                    \
        float wlo_ = wfp[(JJ) * 24 + p_ * 2];                                  \
        float whi_ = wfp[(JJ) * 24 + p_ * 2 + 1];                              \
        _Pragma("unroll")                                                      \
        for (int cc_ = 0; cc_ < 5; ++cc_) {                                    \
            float cv_ = (&CF[cc_].x)[f_];                                      \
            y[cc_][k_][0] = fmaf(cv_, wlo_, y[cc_][k_][0]);                    \
            y[cc_][k_][1] = fmaf(cv_, whi_, y[cc_][k_][1]);                    \
        }                                                                      \
    }                                                                          \
} while (0)

#define LOADCF(CF, ROW) do {                                                   \
    _Pragma("unroll")                                                          \
    for (int cc_ = 0; cc_ < 5; ++cc_)                                          \
        CF[cc_] = Fq[(size_t)((set * 5 + cc_) * 32 + (ROW)) * 64 + lane];      \
} while (0)

__launch_bounds__(1024, 4)
__global__ void k_conv(const float* __restrict__ xin, float* __restrict__ xout,
                       const float4* __restrict__ Fq, const float* __restrict__ pw_l,
                       const float* __restrict__ scale, const float* __restrict__ invs,
                       const float* __restrict__ conv_b_l) {
    const int tid = threadIdx.x;
    const int wq = __builtin_amdgcn_readfirstlane(tid >> 6);   // 0..15, SGPR
    const int lane = tid & 63;
    const float* wxp = pw_l + wq * 832;       // x-part: 64 floats, uniform
    const float* wfp = wxp + 64;              // feats: 768 floats, uniform
    float bx = conv_b_l[wq * 2], by = conv_b_l[wq * 2 + 1];

    const int set = blockIdx.x;               // chunks set*5 .. set*5+4
    const int nl2 = lane >> 2, b2 = lane & 3;

    float y[5][3][2];
    #pragma unroll
    for (int cc = 0; cc < 5; ++cc) {
        y[cc][0][0] = bx; y[cc][0][1] = by;
        y[cc][1][0] = 0.f; y[cc][1][1] = 0.f;
        y[cc][2][0] = 0.f; y[cc][2][1] = 0.f;
    }

    // ---- x part: K rows 0..31 ([n][d][b] layout -> strided dword loads, L1/L2-hot) ----
    #pragma unroll 2
    for (int jg = 0; jg < 8; ++jg) {
        float cxv[5][4];
        #pragma unroll
        for (int cc = 0; cc < 5; ++cc) {
            int n = (set * 5 + cc) * 16 + nl2;
            const float* xb = xin + (size_t)n * 128 + b2;
            #pragma unroll
            for (int dj = 0; dj < 4; ++dj)
                cxv[cc][dj] = xb[(jg * 4 + dj) * 4];
        }
        #pragma unroll
        for (int dj = 0; dj < 4; ++dj) {
            int j = jg * 4 + dj;
            float wlo = wxp[2 * j];
            float whi = wxp[2 * j + 1];
            #pragma unroll
            for (int cc = 0; cc < 5; ++cc) {
                float cv = cxv[cc][dj];
                y[cc][0][0] = fmaf(cv, wlo, y[cc][0][0]);
                y[cc][0][1] = fmaf(cv, whi, y[cc][0][1]);
            }
        }
    }

    // ---- feats: 32 d-blocks, distance-3 pipeline over 4 static buffers ----
    float4 cf0[5], cf1[5], cf2[5], cf3[5];
    LOADCF(cf0, 0);
    LOADCF(cf1, 1);
    LOADCF(cf2, 2);
    #pragma unroll 1
    for (int jj = 0; jj < 32; jj += 4) {
        LOADCF(cf3, jj + 3); FMAB(cf0, jj);
        LOADCF(cf0, jj + 4); FMAB(cf1, jj + 1);   // rows 32..34 read slack (harmless)
        LOADCF(cf1, jj + 5); FMAB(cf2, jj + 2);
        LOADCF(cf2, jj + 6); FMAB(cf3, jj + 3);
    }

    // ---- epilogue: out[n][o][b] scalar stores ----
    #pragma unroll
    for (int cc = 0; cc < 5; ++cc) {
        int n = (set * 5 + cc) * 16 + nl2;
        float scn = scale[n], ivn = invs[n];
        float* xo = xout + (size_t)n * 128 + b2;
        float v0 = fmaxf(0.f, y[cc][0][0] + scn * y[cc][1][0] + ivn * y[cc][2][0]);
        float v1 = fmaxf(0.f, y[cc][0][1] + scn * y[cc][1][1] + ivn * y[cc][2][1]);
        xo[(wq * 2) * 4] = v0;
        xo[(wq * 2 + 1) * 4] = v1;
    }
}

// ---------------- final scoring ----------------
__global__ void k_score(const float* __restrict__ xL, const float* __restrict__ query_emb,
                        const int* __restrict__ r_index, const int* __restrict__ t_index,
                        const float* __restrict__ W1, const float* __restrict__ b1,
                        const float* __restrict__ W2, const float* __restrict__ b2,
                        float* __restrict__ out) {
    int bi = blockIdx.x;            // 0..127
    int b = bi >> 5, kk = bi & 31;
    int j = threadIdx.x;            // 0..63
    __shared__ float sf[64];
    int t = t_index[b * KK + kk];
    float f = (j < DD) ? xL[(size_t)t * 128 + j * 4 + b]
                       : query_emb[r_index[b] * DD + (j - DD)];
    sf[j] = f;
    __syncthreads();
    float acc = b1[j];
    #pragma unroll 8
    for (int i2 = 0; i2 < 64; ++i2) acc = fmaf(sf[i2], W1[j * 64 + i2], acc);
    float h = fmaxf(acc, 0.f);
    float prod = h * W2[j];
    #pragma unroll
    for (int off = 32; off > 0; off >>= 1) prod += __shfl_down(prod, off);
    if (j == 0) out[b * KK + kk] = prod + b2[0];
}

extern "C" void kernel_launch(void* const* d_in, const int* in_sizes, int n_in,
                              void* d_out, int out_size, void* d_ws, size_t ws_size,
                              hipStream_t stream) {
    const int* ei        = (const int*)d_in[0];
    const int* et        = (const int*)d_in[1];
    const int* h_index   = (const int*)d_in[2];
    const int* t_index   = (const int*)d_in[3];
    const int* r_index   = (const int*)d_in[4];
    const float* query_emb = (const float*)d_in[6];
    const float* rel_W   = (const float*)d_in[7];
    const float* rel_b   = (const float*)d_in[8];
    const float* conv_W  = (const float*)d_in[9];
    const float* conv_b  = (const float*)d_in[10];
    const float* W1      = (const float*)d_in[11];
    const float* b1      = (const float*)d_in[12];
    const float* W2      = (const float*)d_in[13];
    const float* b2      = (const float*)d_in[14];

    float* ws = (float*)d_ws;
    float* x0      = ws + OFF_X0;
    float* x1      = ws + OFF_X1;
    int*   row_ptr = (int*)(ws + OFF_RP);
    int*   cursor  = (int*)(ws + OFF_CUR);
    int*   es      = (int*)(ws + OFF_ES);
    float* rdeg    = ws + OFF_DEG;
    float* sc      = ws + OFF_SC;
    float* invs    = ws + OFF_INV;
    int*   bsum    = (int*)(ws + OFF_BS);
    float* blog    = ws + OFF_BL;
    int*   boff    = (int*)(ws + OFF_BO);
    float* meanw   = ws + OFF_MEAN;
    float* rel_all = ws + OFF_REL;
    float* pw      = ws + OFF_PW;
    float4* Fq     = (float4*)(ws + OFF_F);
    float* out     = (float*)d_out;

    // prep
    k_init<<<1024, 256, 0, stream>>>(h_index, r_index, query_emb, x0, cursor);
    k_hist<<<(N_EDGES + 255) / 256, 256, 0, stream>>>(ei, cursor);
    k_part<<<NBLK, 256, 0, stream>>>(cursor, bsum, blog);
    k_scan2<<<1, 128, 0, stream>>>(bsum, blog, boff, meanw);
    k_final<<<NBLK, 256, 0, stream>>>(cursor, row_ptr, boff, meanw, rdeg, sc, invs);
    k_scatter<<<(N_EDGES + 255) / 256, 256, 0, stream>>>(ei, et, cursor, es);
    const int NPREP = LL * BB * RR * DD + LL * 16 * 832;
    k_prep_w<<<(NPREP + 255) / 256, 256, 0, stream>>>(query_emb, r_index, rel_W, rel_b,
                                                      conv_W, rel_all, pw);

    // 4 BF layers, ping-pong x0/x1
    for (int l = 0; l < LL; ++l) {
        const float* xi = (l & 1) ? x1 : x0;
        float* xo = (l & 1) ? x0 : x1;
        k_gather<<<1536, 256, 0, stream>>>(xi, Fq, row_ptr, es,
                                           rel_all + (size_t)l * RR * BB * DD,
                                           rdeg, h_index, r_index, query_emb);
        k_conv<<<250, 1024, 0, stream>>>(xi, xo, Fq, pw + (size_t)l * 16 * 832,
                                         sc, invs, conv_b + l * DD);
    }

    k_score<<<BB * KK, 64, 0, stream>>>(x0, query_emb, r_index, t_index, W1, b1, W2, b2, out);
}

// Round 11
// 266.996 us; speedup vs baseline: 8.7085x; 1.2087x over previous
//
#include <hip/hip_runtime.h>
#include <hip/hip_bf16.h>

// NBFNet Bellman-Ford pass, MI355X. N=20000, E=200000, B=4, K=32, D=32, R=36, L=4.
// x layout: [n][d][b] (b innermost) -> gather reads one dwordx4 per edge per lane.
#define N_NODES 20000
#define N_EDGES 200000
#define BB 4
#define KK 32
#define DD 32
#define RR 36
#define LL 4
#define NCHUNKS (N_NODES / 16)   // 1250
#define NBLK 79                  // ceil(20000/256)

// ---------------- ws layout (element offsets, 4B units) ----------------
constexpr size_t OFF_X0   = 0;                                        // float[N*D*B], x[(n*32+d)*4+b]
constexpr size_t OFF_X1   = OFF_X0 + (size_t)BB * N_NODES * DD;
constexpr size_t OFF_RP   = OFF_X1 + (size_t)BB * N_NODES * DD;       // int[N+1]
constexpr size_t OFF_CUR  = OFF_RP + 20032;                           // int[N]
constexpr size_t OFF_ES   = OFF_CUR + N_NODES;                        // int[E] src | type<<16
constexpr size_t OFF_DEG  = OFF_ES + N_EDGES;                         // float[N] 1/deg
constexpr size_t OFF_SC   = OFF_DEG + N_NODES;                        // float[N] scale
constexpr size_t OFF_INV  = OFF_SC + N_NODES;                         // float[N] 1/max(scale,.01)
constexpr size_t OFF_BS   = OFF_INV + N_NODES;                        // int[128] block sums
constexpr size_t OFF_BL   = OFF_BS + 128;                             // float[128] block log sums
constexpr size_t OFF_BO   = OFF_BL + 128;                             // int[128] block offsets
constexpr size_t OFF_MEAN = OFF_BO + 128;                             // float[16]
constexpr size_t OFF_REL  = OFF_MEAN + 16;                            // float[L*R*D*B] [l][ty][d][b]
constexpr size_t OFF_PW   = OFF_REL + (size_t)LL * RR * BB * DD;      // float[L*4*3328]
constexpr size_t OFF_F    = OFF_PW + (size_t)LL * 4 * 3328;           // float4[(NCHUNKS*32+64)*64]
// Fq keeps 64 rows of slack: the ping-pong prefetch reads 1 row past each chunk.

// ---------------- prep kernels ----------------

__global__ void k_init(const int* __restrict__ h_index, const int* __restrict__ r_index,
                       const float* __restrict__ query_emb, float* __restrict__ x0,
                       int* __restrict__ cursor) {
    int i = blockIdx.x * blockDim.x + threadIdx.x;
    int stride = gridDim.x * blockDim.x;
    for (int t = i; t < N_NODES; t += stride) cursor[t] = 0;
    for (int t = i; t < BB * N_NODES * DD; t += stride) {
        int b = t & 3; int d = (t >> 2) & 31; int n = t >> 7;
        float v = 0.f;
        if (n == h_index[b]) v = query_emb[r_index[b] * DD + d];
        x0[t] = v;
    }
}

__global__ void k_hist(const int* __restrict__ ei, int* __restrict__ cursor) {
    int e = blockIdx.x * blockDim.x + threadIdx.x;
    if (e < N_EDGES) atomicAdd(&cursor[ei[N_EDGES + e]], 1);
}

// per-block partial sums of deg histogram + log(deg)
__global__ void k_part(const int* __restrict__ cursor, int* __restrict__ bsum,
                       float* __restrict__ blog) {
    __shared__ int si[256];
    __shared__ float sf2[256];
    int tid = threadIdx.x;
    int i = blockIdx.x * 256 + tid;
    int v = (i < N_NODES) ? cursor[i] : 0;
    float lg = (i < N_NODES) ? logf((float)(v + 1)) : 0.f;
    si[tid] = v; sf2[tid] = lg;
    __syncthreads();
    for (int off = 128; off > 0; off >>= 1) {
        if (tid < off) { si[tid] += si[tid + off]; sf2[tid] += sf2[tid + off]; }
        __syncthreads();
    }
    if (tid == 0) { bsum[blockIdx.x] = si[0]; blog[blockIdx.x] = sf2[0]; }
}

// single small block: scan the 79 block sums; total log -> mean
__global__ void k_scan2(const int* __restrict__ bsum, const float* __restrict__ blog,
                        int* __restrict__ boff, float* __restrict__ meanw) {
    __shared__ int si[128];
    __shared__ float sf2[128];
    int t = threadIdx.x;
    int v = (t < NBLK) ? bsum[t] : 0;
    float lg = (t < NBLK) ? blog[t] : 0.f;
    si[t] = v; sf2[t] = lg;
    __syncthreads();
    for (int off = 1; off < 128; off <<= 1) {
        int tv = (t >= off) ? si[t - off] : 0;
        float tf = (t >= off) ? sf2[t - off] : 0.f;
        __syncthreads();
        si[t] += tv; sf2[t] += tf;
        __syncthreads();
    }
    if (t < NBLK) boff[t] = si[t] - v;                      // exclusive
    if (t == 127) meanw[0] = sf2[127] / (float)N_NODES;     // mean(log deg)
}

// per-block scan + global offset -> row_ptr/cursor; rdeg/scale/inv
__global__ void k_final(int* __restrict__ cursor, int* __restrict__ row_ptr,
                        const int* __restrict__ boff, const float* __restrict__ meanw,
                        float* __restrict__ rdeg, float* __restrict__ scale,
                        float* __restrict__ invs) {
    __shared__ int si[256];
    int tid = threadIdx.x;
    int i = blockIdx.x * 256 + tid;
    int v = (i < N_NODES) ? cursor[i] : 0;
    si[tid] = v;
    __syncthreads();
    for (int off = 1; off < 256; off <<= 1) {
        int tv = (tid >= off) ? si[tid - off] : 0;
        __syncthreads();
        si[tid] += tv;
        __syncthreads();
    }
    int rp = boff[blockIdx.x] + si[tid] - v;   // exclusive prefix
    if (i < N_NODES) {
        row_ptr[i] = rp;
        cursor[i] = rp;
        float dg = (float)(v + 1);
        float sc = logf(dg) / meanw[0];
        rdeg[i] = 1.f / dg;
        scale[i] = sc;
        invs[i] = 1.f / fmaxf(sc, 0.01f);
    }
    if (i == 0) row_ptr[N_NODES] = N_EDGES;
}

__global__ void k_scatter(const int* __restrict__ ei, const int* __restrict__ et,
                          int* __restrict__ cursor, int* __restrict__ es) {
    int e = blockIdx.x * blockDim.x + threadIdx.x;
    if (e < N_EDGES) {
        int dnode = ei[N_EDGES + e];
        int p = atomicAdd(&cursor[dnode], 1);
        es[p] = ei[e] | (et[e] << 16);
    }
}

// rel tables [l][ty][d][b] + prepped conv weights.
// pw layout per (l, og), og in [0,4) covering outputs o = og*8 .. og*8+7 (3328 floats):
//   r in [0,256):   x-part.  j = r>>3, o = og*8 + (r&7)      -> idx j*8 + (o&7)
//   r in [256,3328): feats.  r2=r-256; jj=r2/96; rem=r2%96; pf=rem>>3 (= f*3+k);
//                   o = og*8 + (rem&7); col = 32 + (jj*4 + pf/3)*3 + pf%3
__global__ void k_prep_w(const float* __restrict__ query_emb, const int* __restrict__ r_index,
                         const float* __restrict__ rel_W, const float* __restrict__ rel_b,
                         const float* __restrict__ conv_W,
                         float* __restrict__ rel_all, float* __restrict__ pw) {
    int i = blockIdx.x * blockDim.x + threadIdx.x;
    const int NREL = LL * BB * RR * DD;
    if (i < NREL) {
        int d = i & 31;
        int ty = (i >> 5) % RR;
        int b = (i / (32 * RR)) & 3;
        int l = i / (32 * RR * BB);
        const float* q = query_emb + r_index[b] * DD;
        const float* w = rel_W + ((size_t)l * RR * DD + ty * DD + d) * DD;
        float acc = rel_b[l * RR * DD + ty * DD + d];
        #pragma unroll
        for (int k2 = 0; k2 < DD; ++k2) acc = fmaf(q[k2], w[k2], acc);
        rel_all[(((size_t)l * RR + ty) * DD + d) * BB + b] = acc;
    } else {
        int i2 = i - NREL;
        if (i2 >= LL * 4 * 3328) return;
        int r = i2 % 3328; int lg2 = i2 / 3328;
        int og = lg2 & 3, l = lg2 >> 2;
        int o, col;
        if (r < 256) { col = r >> 3; o = og * 8 + (r & 7); }
        else {
            int r2 = r - 256;
            int jj = r2 / 96, rem = r2 % 96;
            int pf = rem >> 3;
            o = og * 8 + (rem & 7);
            col = DD + (jj * 4 + pf / 3) * 3 + (pf % 3);
        }
        pw[i2] = conv_W[(size_t)(l * DD + o) * (13 * DD) + col];
    }
}

// ---------------- gather + PNA kernel ----------------
// Wave per node (grid-stride). lane = d + 32*par; parity halves process alternate
// edges (4-deep unroll = 8 x-row dwordx4 loads in flight per wave); shfl_xor(32) combine.
// Writes F transposed: Fq[(chunk*32 + d)*64 + task] = {mean,max,min,std}.
__launch_bounds__(256, 6)
__global__ void k_gather(const float* __restrict__ xin, float4* __restrict__ Fq,
                         const int* __restrict__ row_ptr, const int* __restrict__ es,
                         const float* __restrict__ rel_l, const float* __restrict__ rdeg,
                         const int* __restrict__ h_index, const int* __restrict__ r_index,
                         const float* __restrict__ query_emb) {
    __shared__ __align__(16) float s_rel[RR * BB * DD];   // 18432 B, [ty][d][b]
    const int tid = threadIdx.x;
    {   // stage rel table once per block
        const float4* p4 = (const float4*)rel_l;
        float4* s4 = (float4*)s_rel;
        for (int i = tid; i < RR * BB * DD / 4; i += 256) s4[i] = p4[i];
    }
    const int lane = tid & 63;
    const int d = lane & 31;
    const int par = lane >> 5;
    int hb[4]; float qv[4];
    #pragma unroll
    for (int b = 0; b < 4; ++b) {
        hb[b] = h_index[b];
        qv[b] = query_emb[r_index[b] * DD + d];
    }
    __syncthreads();

    const int nwaves = gridDim.x * 4;
    for (int n = blockIdx.x * 4 + (tid >> 6); n < N_NODES; n += nwaves) {
        float sa[4], sq[4], mx[4], mn[4];
        #pragma unroll
        for (int b = 0; b < 4; ++b) {
            float bv = (n == hb[b]) ? qv[b] : 0.f;
            float bs = par ? 0.f : bv;        // count boundary message once in sum/sq
            sa[b] = bs; sq[b] = bs * bv; mx[b] = bv; mn[b] = bv;
        }
        auto proc = [&](int ee) {
            int pk = es[ee];
            float4 xv = *(const float4*)(xin + ((size_t)(pk & 0xFFFF) * DD + d) * 4);
            float4 rv = *(const float4*)(s_rel + (((pk >> 16) * DD) + d) * 4);
            #pragma unroll
            for (int b = 0; b < 4; ++b) {
                float m = (&xv.x)[b] * (&rv.x)[b];
                sa[b] += m; sq[b] = fmaf(m, m, sq[b]);
                mx[b] = fmaxf(mx[b], m); mn[b] = fminf(mn[b], m);
            }
        };
        int e0 = row_ptr[n], e1 = row_ptr[n + 1];
        int e = e0 + par;                        // parity-strided: 2 edges per step
        for (; e + 6 < e1; e += 8) { proc(e); proc(e + 2); proc(e + 4); proc(e + 6); }
        for (; e < e1; e += 2) proc(e);
        #pragma unroll
        for (int b = 0; b < 4; ++b) {
            sa[b] += __shfl_xor(sa[b], 32);
            sq[b] += __shfl_xor(sq[b], 32);
            mx[b] = fmaxf(mx[b], __shfl_xor(mx[b], 32));
            mn[b] = fminf(mn[b], __shfl_xor(mn[b], 32));
        }
        float rd_ = rdeg[n];
        float mean[4], sd[4];
        #pragma unroll
        for (int b = 0; b < 4; ++b) {
            mean[b] = sa[b] * rd_;
            float sm = sq[b] * rd_;
            sd[b] = sqrtf(fmaxf(sm - mean[b] * mean[b], 1e-6f));
        }
        const int chunk = n >> 4, nl = n & 15;
        int tA = nl * 4 + par * 2;               // each half writes 2 tasks
        float4 fA, fB;
        fA.x = par ? mean[2] : mean[0]; fA.y = par ? mx[2] : mx[0];
        fA.z = par ? mn[2] : mn[0];     fA.w = par ? sd[2] : sd[0];
        fB.x = par ? mean[3] : mean[1]; fB.y = par ? mx[3] : mx[1];
        fB.z = par ? mn[3] : mn[1];     fB.w = par ? sd[3] : sd[1];
        Fq[(size_t)(chunk * 32 + d) * 64 + tA] = fA;
        Fq[(size_t)(chunk * 32 + d) * 64 + tA + 1] = fB;
    }
}

// ---------------- conv kernel ----------------
// r11: one chunk per 256-thr block (grid = 1250, all blocks co-resident at
// 6 blocks/CU -> perfect balance). 4 waves = 4 out-groups of 8 outputs; lane =
// task. F-operand redundancy drops 16x -> 4x (the r6-r10 limiter: every wave
// re-read the whole Fq tile through L1; TCP ~82K cyc/CU vs 33K VALU). Weights
// stay on the scalar path (uniform base + compile-time offsets -> s_load,
// K$/L2-hot, no LDS, no barriers). Per-chunk pipes now: VALU 6.7K > TCP ~4K.
__launch_bounds__(256, 6)
__global__ void k_conv(const float* __restrict__ xin, float* __restrict__ xout,
                       const float4* __restrict__ Fq, const float* __restrict__ pw_l,
                       const float* __restrict__ scale, const float* __restrict__ invs,
                       const float* __restrict__ conv_b_l) {
    const int tid = threadIdx.x;
    const int og = __builtin_amdgcn_readfirstlane(tid >> 6);   // 0..3, SGPR
    const int lane = tid & 63;
    const int chunk = blockIdx.x;
    const float* wxp = pw_l + og * 3328;      // x weights [32 j][8 o], uniform
    const float* wfp = wxp + 256;             // feat weights [32 jj][12 pf][8 o], uniform

    const int nl2 = lane >> 2, b2 = lane & 3;
    const int n = chunk * 16 + nl2;

    float y0[8], y1[8], y2[8];
    #pragma unroll
    for (int oo = 0; oo < 8; ++oo) {
        y0[oo] = conv_b_l[og * 8 + oo];
        y1[oo] = 0.f;
        y2[oo] = 0.f;
    }

    // ---- x part: 32 K-rows ([n][d][b] layout) ----
    const float* xb = xin + (size_t)n * 128 + b2;
    #pragma unroll 2
    for (int jg = 0; jg < 8; ++jg) {
        float cxv[4];
        #pragma unroll
        for (int dj = 0; dj < 4; ++dj) cxv[dj] = xb[(jg * 4 + dj) * 4];
        #pragma unroll
        for (int dj = 0; dj < 4; ++dj) {
            const float* wp = wxp + (jg * 4 + dj) * 8;
            #pragma unroll
            for (int oo = 0; oo < 8; ++oo) y0[oo] = fmaf(cxv[dj], wp[oo], y0[oo]);
        }
    }

    // ---- feats: 32 d-rows, f = mean/max/min/std, k-sets via y0/y1/y2 ----
    float4 fa = Fq[(size_t)(chunk * 32) * 64 + lane];
    #pragma unroll 1
    for (int jj = 0; jj < 32; ++jj) {
        float4 fb = Fq[(size_t)(chunk * 32 + jj + 1) * 64 + lane];  // slack row at end
        const float* wp = wfp + jj * 96;
        #pragma unroll
        for (int f = 0; f < 4; ++f) {
            float cv = (&fa.x)[f];
            const float* w8 = wp + f * 24;    // pf = f*3+k -> f*24 + k*8 + o
            #pragma unroll
            for (int oo = 0; oo < 8; ++oo) y0[oo] = fmaf(cv, w8[oo], y0[oo]);
            #pragma unroll
            for (int oo = 0; oo < 8; ++oo) y1[oo] = fmaf(cv, w8[8 + oo], y1[oo]);
            #pragma unroll
            for (int oo = 0; oo < 8; ++oo) y2[oo] = fmaf(cv, w8[16 + oo], y2[oo]);
        }
        fa = fb;
    }

    // ---- epilogue: out[n][o][b] scalar stores ----
    float scn = scale[n], ivn = invs[n];
    float* xo = xout + (size_t)n * 128 + b2;
    #pragma unroll
    for (int oo = 0; oo < 8; ++oo) {
        float v = fmaxf(0.f, y0[oo] + scn * y1[oo] + ivn * y2[oo]);
        xo[(og * 8 + oo) * 4] = v;
    }
}

// ---------------- final scoring ----------------
__global__ void k_score(const float* __restrict__ xL, const float* __restrict__ query_emb,
                        const int* __restrict__ r_index, const int* __restrict__ t_index,
                        const float* __restrict__ W1, const float* __restrict__ b1,
                        const float* __restrict__ W2, const float* __restrict__ b2,
                        float* __restrict__ out) {
    int bi = blockIdx.x;            // 0..127
    int b = bi >> 5, kk = bi & 31;
    int j = threadIdx.x;            // 0..63
    __shared__ float sf[64];
    int t = t_index[b * KK + kk];
    float f = (j < DD) ? xL[(size_t)t * 128 + j * 4 + b]
                       : query_emb[r_index[b] * DD + (j - DD)];
    sf[j] = f;
    __syncthreads();
    float acc = b1[j];
    #pragma unroll 8
    for (int i2 = 0; i2 < 64; ++i2) acc = fmaf(sf[i2], W1[j * 64 + i2], acc);
    float h = fmaxf(acc, 0.f);
    float prod = h * W2[j];
    #pragma unroll
    for (int off = 32; off > 0; off >>= 1) prod += __shfl_down(prod, off);
    if (j == 0) out[b * KK + kk] = prod + b2[0];
}

extern "C" void kernel_launch(void* const* d_in, const int* in_sizes, int n_in,
                              void* d_out, int out_size, void* d_ws, size_t ws_size,
                              hipStream_t stream) {
    const int* ei        = (const int*)d_in[0];
    const int* et        = (const int*)d_in[1];
    const int* h_index   = (const int*)d_in[2];
    const int* t_index   = (const int*)d_in[3];
    const int* r_index   = (const int*)d_in[4];
    const float* query_emb = (const float*)d_in[6];
    const float* rel_W   = (const float*)d_in[7];
    const float* rel_b   = (const float*)d_in[8];
    const float* conv_W  = (const float*)d_in[9];
    const float* conv_b  = (const float*)d_in[10];
    const float* W1      = (const float*)d_in[11];
    const float* b1      = (const float*)d_in[12];
    const float* W2      = (const float*)d_in[13];
    const float* b2      = (const float*)d_in[14];

    float* ws = (float*)d_ws;
    float* x0      = ws + OFF_X0;
    float* x1      = ws + OFF_X1;
    int*   row_ptr = (int*)(ws + OFF_RP);
    int*   cursor  = (int*)(ws + OFF_CUR);
    int*   es      = (int*)(ws + OFF_ES);
    float* rdeg    = ws + OFF_DEG;
    float* sc      = ws + OFF_SC;
    float* invs    = ws + OFF_INV;
    int*   bsum    = (int*)(ws + OFF_BS);
    float* blog    = ws + OFF_BL;
    int*   boff    = (int*)(ws + OFF_BO);
    float* meanw   = ws + OFF_MEAN;
    float* rel_all = ws + OFF_REL;
    float* pw      = ws + OFF_PW;
    float4* Fq     = (float4*)(ws + OFF_F);
    float* out     = (float*)d_out;

    // prep
    k_init<<<1024, 256, 0, stream>>>(h_index, r_index, query_emb, x0, cursor);
    k_hist<<<(N_EDGES + 255) / 256, 256, 0, stream>>>(ei, cursor);
    k_part<<<NBLK, 256, 0, stream>>>(cursor, bsum, blog);
    k_scan2<<<1, 128, 0, stream>>>(bsum, blog, boff, meanw);
    k_final<<<NBLK, 256, 0, stream>>>(cursor, row_ptr, boff, meanw, rdeg, sc, invs);
    k_scatter<<<(N_EDGES + 255) / 256, 256, 0, stream>>>(ei, et, cursor, es);
    const int NPREP = LL * BB * RR * DD + LL * 4 * 3328;
    k_prep_w<<<(NPREP + 255) / 256, 256, 0, stream>>>(query_emb, r_index, rel_W, rel_b,
                                                      conv_W, rel_all, pw);

    // 4 BF layers, ping-pong x0/x1
    for (int l = 0; l < LL; ++l) {
        const float* xi = (l & 1) ? x1 : x0;
        float* xo = (l & 1) ? x0 : x1;
        k_gather<<<1536, 256, 0, stream>>>(xi, Fq, row_ptr, es,
                                           rel_all + (size_t)l * RR * BB * DD,
                                           rdeg, h_index, r_index, query_emb);
        k_conv<<<NCHUNKS, 256, 0, stream>>>(xi, xo, Fq, pw + (size_t)l * 4 * 3328,
                                            sc, invs, conv_b + l * DD);
    }

    k_score<<<BB * KK, 64, 0, stream>>>(x0, query_emb, r_index, t_index, W1, b1, W2, b2, out);
}